// Round 3
// baseline (2155.829 us; speedup 1.0000x reference)
//
#include <hip/hip_runtime.h>
#include <hip/hip_bf16.h>
#include <math.h>

typedef __hip_bfloat16 bf16;

#define NN 50000
#define EE 400000
#define FIN 262
#define HID 128
#define NH 4
#define C1 512   /* HID*NH */
#define NGR 16

__device__ __forceinline__ float b2f(bf16 x){ return __bfloat162float(x); }
__device__ __forceinline__ bf16 f2b(float x){ return __float2bfloat16(x); }
__device__ __forceinline__ float ldA(const bf16* p, size_t i){ return __bfloat162float(p[i]); }
__device__ __forceinline__ float ldA(const float* p, size_t i){ return p[i]; }
__device__ __forceinline__ void stC(float* p, size_t i, float v){ p[i] = v; }
__device__ __forceinline__ void stC(bf16* p, size_t i, float v){ p[i] = f2b(v); }

__global__ void zero_words(unsigned int* __restrict__ p, int n) {
  int i = blockIdx.x * 256 + threadIdx.x;
  if (i < n) p[i] = 0u;
}

// ---- tiled GEMM: C(MxN) = A(MxK) @ B(KxN); A bf16/f32, B f32 row-major, C bf16/f32
template<typename TA, typename TC>
__global__ void gemm_tiled(const TA* __restrict__ A, const float* __restrict__ B,
                           TC* __restrict__ C, int M, int K, int Ncols) {
  __shared__ float As[16][65];
  __shared__ float Bs[16][65];
  int bm = blockIdx.y * 64, bn = blockIdx.x * 64;
  int tid = threadIdx.x;
  int tm = (tid >> 4) << 2;
  int tn = (tid & 15) << 2;
  float acc[4][4] = {};
  for (int k0 = 0; k0 < K; k0 += 16) {
    #pragma unroll
    for (int l = 0; l < 4; ++l) {
      int e = tid + 256 * l;
      int m = e >> 4, kk = e & 15;
      int gm = bm + m, gk = k0 + kk;
      As[kk][m] = (gm < M && gk < K) ? ldA(A, (size_t)gm * K + gk) : 0.f;
      int k2 = e >> 6, n2 = e & 63;
      int gk2 = k0 + k2, gn = bn + n2;
      Bs[k2][n2] = (gk2 < K && gn < Ncols) ? B[(size_t)gk2 * Ncols + gn] : 0.f;
    }
    __syncthreads();
    #pragma unroll
    for (int kk = 0; kk < 16; ++kk) {
      float a[4], b[4];
      #pragma unroll
      for (int i = 0; i < 4; ++i) { a[i] = As[kk][tm + i]; b[i] = Bs[kk][tn + i]; }
      #pragma unroll
      for (int i = 0; i < 4; ++i)
        #pragma unroll
        for (int j = 0; j < 4; ++j)
          acc[i][j] += a[i] * b[j];
    }
    __syncthreads();
  }
  #pragma unroll
  for (int i = 0; i < 4; ++i) {
    int gm = bm + tm + i; if (gm >= M) continue;
    #pragma unroll
    for (int j = 0; j < 4; ++j) {
      int gn = bn + tn + j; if (gn >= Ncols) continue;
      stC(C, (size_t)gm * Ncols + gn, acc[i][j]);
    }
  }
}

// per-node dot of Wh row (128 wide) with a_src/a_dst (f32); one wave per node
template<typename T>
__global__ void edot_kernel(const T* __restrict__ Wh, const float* __restrict__ av,
                            const float* __restrict__ bv, float* __restrict__ es,
                            float* __restrict__ ed, int n) {
  int wid = threadIdx.x >> 6, lane = threadIdx.x & 63;
  int r = blockIdx.x * 4 + wid;
  if (r >= n) return;
  const T* row = Wh + (size_t)r * HID;
  float w0 = ldA(row, lane), w1 = ldA(row, lane + 64);
  float s1 = w0 * av[lane] + w1 * av[lane + 64];
  float s2 = w0 * bv[lane] + w1 * bv[lane + 64];
  #pragma unroll
  for (int off = 32; off > 0; off >>= 1) {
    s1 += __shfl_xor(s1, off);
    s2 += __shfl_xor(s2, off);
  }
  if (lane == 0) { es[r] = s1; ed[r] = s2; }
}

// ---------------- CSR build (guarded) ----------------
__global__ void count_kernel(const int* __restrict__ dst, int* __restrict__ deg, int E) {
  int e = blockIdx.x * blockDim.x + threadIdx.x;
  if (e >= E) return;
  int d = dst[e];
  if ((unsigned)d < NN) atomicAdd(&deg[d], 1);
}

__global__ void scan_kernel(const int* __restrict__ deg, int* __restrict__ rowptr,
                            int* __restrict__ cursor, int n) {
  __shared__ int part[1024];
  int t = threadIdx.x;
  int chunk = (n + 1023) >> 10;
  int lo = t * chunk, hi = min(lo + chunk, n);
  int s = 0;
  for (int i = lo; i < hi; ++i) s += deg[i];
  part[t] = s;
  __syncthreads();
  if (t == 0) {
    int r = 0;
    for (int i = 0; i < 1024; ++i) { int v = part[i]; part[i] = r; r += v; }
  }
  __syncthreads();
  int r = part[t];
  for (int i = lo; i < hi; ++i) { rowptr[i] = r; cursor[i] = r; r += deg[i]; }
  if (lo < n && hi == n) rowptr[n] = r;
}

__global__ void scatter_kernel(const int* __restrict__ dst, int* __restrict__ cursor,
                               int* __restrict__ csr, int E) {
  int e = blockIdx.x * blockDim.x + threadIdx.x;
  if (e >= E) return;
  int d = dst[e];
  if ((unsigned)d >= NN) return;
  int p = atomicAdd(&cursor[d], 1);
  if ((unsigned)p < (unsigned)E) csr[p] = e;
}

// ---- layer-1, one head: edge softmax + aggregate; one wave per dst node ----
__global__ void agg1h_kernel(const int* __restrict__ src, const int* __restrict__ rowptr,
                             const int* __restrict__ csr,
                             const float* __restrict__ es, const float* __restrict__ edv,
                             const bf16* __restrict__ Whh, bf16* __restrict__ h1,
                             int coloff) {
  int wid = threadIdx.x >> 6, lane = threadIdx.x & 63;
  int node = blockIdx.x * 4 + wid;
  if (node >= NN) return;
  int b = rowptr[node], e = rowptr[node + 1];
  if (b < 0) b = 0; if (e > EE) e = EE;
  float ed = edv[node];
  float m = 0.f;  // e_max = max(seg_max, 0)
  for (int j = b; j < e; ++j) {
    int id = csr[j]; if ((unsigned)id >= EE) continue;
    int s = src[id]; if ((unsigned)s >= NN) s = 0;
    float v = es[s] + ed;
    v = v >= 0.f ? v : 0.2f * v;
    m = fmaxf(m, v);
  }
  float sum = 0.f, a0 = 0.f, a1 = 0.f;
  for (int j = b; j < e; ++j) {
    int id = csr[j]; if ((unsigned)id >= EE) continue;
    int s = src[id]; if ((unsigned)s >= NN) s = 0;
    float v = es[s] + ed;
    v = v >= 0.f ? v : 0.2f * v;
    float p = expf(v - m);
    sum += p;
    const bf16* wr = Whh + (size_t)s * HID;
    a0 += p * b2f(wr[lane]);
    a1 += p * b2f(wr[lane + 64]);
  }
  float scale = 1.f / (sum + 1e-8f);
  bf16* orow = h1 + (size_t)node * C1 + coloff;
  orow[lane] = f2b(a0 * scale);
  orow[lane + 64] = f2b(a1 * scale);
}

// ---- layer-2 (H=1): aggregate + attn output (f32) ----
__global__ void agg2_kernel(const int* __restrict__ src, const int* __restrict__ rowptr,
                            const int* __restrict__ csr,
                            const float* __restrict__ es, const float* __restrict__ edv,
                            const float* __restrict__ Wh, bf16* __restrict__ out,
                            float* __restrict__ attn_out) {
  int wid = threadIdx.x >> 6, lane = threadIdx.x & 63;
  int node = blockIdx.x * 4 + wid;
  if (node >= NN) return;
  int b = rowptr[node], e = rowptr[node + 1];
  if (b < 0) b = 0; if (e > EE) e = EE;
  float ed = edv[node];
  float m = 0.f;
  for (int j = b; j < e; ++j) {
    int id = csr[j]; if ((unsigned)id >= EE) continue;
    int s = src[id]; if ((unsigned)s >= NN) s = 0;
    float v = es[s] + ed;
    v = v >= 0.f ? v : 0.2f * v;
    m = fmaxf(m, v);
  }
  float sum = 0.f, a0 = 0.f, a1 = 0.f;
  for (int j = b; j < e; ++j) {
    int id = csr[j]; if ((unsigned)id >= EE) continue;
    int s = src[id]; if ((unsigned)s >= NN) s = 0;
    float v = es[s] + ed;
    v = v >= 0.f ? v : 0.2f * v;
    float p = expf(v - m);
    sum += p;
    a0 += p * Wh[(size_t)s * HID + lane];
    a1 += p * Wh[(size_t)s * HID + lane + 64];
  }
  float scale = 1.f / (sum + 1e-8f);
  out[(size_t)node * HID + lane] = f2b(a0 * scale);
  out[(size_t)node * HID + lane + 64] = f2b(a1 * scale);
  for (int j = b; j < e; ++j) {
    int id = csr[j]; if ((unsigned)id >= EE) continue;
    int s = src[id]; if ((unsigned)s >= NN) s = 0;
    float v = es[s] + ed;
    v = v >= 0.f ? v : 0.2f * v;
    if (lane == 0) attn_out[id] = expf(v - m) * scale;
  }
}

// ---- ELU in place (bf16) + per-column fp32 sum/sumsq; blockDim == C ----
__global__ void elu_stats(bf16* __restrict__ X, float* __restrict__ cs, float* __restrict__ cq,
                          int Nrows, int C) {
  int c = threadIdx.x;
  int rpb = (Nrows + gridDim.x - 1) / gridDim.x;
  int r0 = blockIdx.x * rpb, r1 = min(r0 + rpb, Nrows);
  float s = 0.f, s2 = 0.f;
  for (int r = r0; r < r1; ++r) {
    size_t idx = (size_t)r * C + c;
    float v = b2f(X[idx]);
    v = v > 0.f ? v : expm1f(v);
    X[idx] = f2b(v);
    s += v; s2 += v * v;
  }
  atomicAdd(&cs[c], s);
  atomicAdd(&cq[c], s2);
}

__global__ void bn_apply(const bf16* __restrict__ in, bf16* __restrict__ out,
                         float* __restrict__ out2,
                         const float* __restrict__ cs, const float* __restrict__ cq,
                         const float* __restrict__ gamma, const float* __restrict__ beta,
                         int C, size_t total, float invN) {
  size_t i = (size_t)blockIdx.x * blockDim.x + threadIdx.x;
  if (i >= total) return;
  int c = (int)(i % C);
  float mu = cs[c] * invN;
  float var = cq[c] * invN - mu * mu;
  float v = (b2f(in[i]) - mu) * rsqrtf(fmaxf(var, 0.f) + 1e-5f) * gamma[c] + beta[c];
  out[i] = f2b(v);
  if (out2) out2[i] = v;
}

// ---- global mean pool ----
__global__ void pool_kernel(const bf16* __restrict__ h2, const int* __restrict__ batch,
                            float* __restrict__ pooled, float* __restrict__ cnt) {
  __shared__ float acc[NGR * HID];
  __shared__ float ccnt[NGR];
  int f = threadIdx.x;  // 128 threads
  for (int i = f; i < NGR * HID; i += HID) acc[i] = 0.f;
  if (f < NGR) ccnt[f] = 0.f;
  __syncthreads();
  for (int r = blockIdx.x; r < NN; r += gridDim.x) {
    int g = batch[r]; if ((unsigned)g >= NGR) g = 0;
    acc[g * HID + f] += b2f(h2[(size_t)r * HID + f]);
    if (f == 0) ccnt[g] += 1.f;
  }
  __syncthreads();
  for (int i = f; i < NGR * HID; i += HID) atomicAdd(&pooled[i], acc[i]);
  if (f < NGR) atomicAdd(&cnt[f], ccnt[f]);
}

// ---- classifier (tiny, single block), f32 weights/out ----
__global__ void cls_kernel(const float* __restrict__ pooled, const float* __restrict__ cnt,
                           const float* __restrict__ w1, const float* __restrict__ b1,
                           const float* __restrict__ w2, const float* __restrict__ b2,
                           float* __restrict__ out) {
  __shared__ float repr[NGR * HID];
  __shared__ float hid[NGR * 64];
  int t = threadIdx.x;  // 128
  for (int i = t; i < NGR * HID; i += 128) {
    int g = i >> 7;
    repr[i] = pooled[i] / fmaxf(cnt[g], 1.f);
  }
  __syncthreads();
  for (int i = t; i < NGR * 64; i += 128) {
    int g = i >> 6, j = i & 63;
    float s = b1[j];
    for (int c = 0; c < HID; ++c) s += repr[g * HID + c] * w1[c * 64 + j];
    hid[i] = fmaxf(s, 0.f);
  }
  __syncthreads();
  if (t < NGR * 2) {
    int g = t >> 1, k = t & 1;
    float s = b2[k];
    for (int j = 0; j < 64; ++j) s += hid[g * 64 + j] * w2[j * 2 + k];
    out[t] = s;
  }
}

// ---- edge importance: relu(P[src]+Q[dst]+b1)·w2 + b2 → sigmoid; wave per edge ----
__global__ void eimp_kernel(const int* __restrict__ src, const int* __restrict__ dstp,
                            const bf16* __restrict__ P, const bf16* __restrict__ Q,
                            const float* __restrict__ b1, const float* __restrict__ w2,
                            const float* __restrict__ b2, float* __restrict__ out) {
  int wid = threadIdx.x >> 6, lane = threadIdx.x & 63;
  int e = blockIdx.x * 4 + wid;
  if (e >= EE) return;
  int s = src[e]; if ((unsigned)s >= NN) s = 0;
  int d = dstp[e]; if ((unsigned)d >= NN) d = 0;
  float acc = 0.f;
  #pragma unroll
  for (int r = 0; r < 2; ++r) {
    int j = lane + 64 * r;
    float h = b2f(P[(size_t)s * HID + j]) + b2f(Q[(size_t)d * HID + j]) + b1[j];
    h = fmaxf(h, 0.f);
    acc += h * w2[j];
  }
  #pragma unroll
  for (int off = 32; off > 0; off >>= 1) acc += __shfl_xor(acc, off);
  if (lane == 0) {
    float z = acc + b2[0];
    out[e] = 1.f / (1.f + expf(-z));
  }
}

extern "C" void kernel_launch(void* const* d_in, const int* in_sizes, int n_in,
                              void* d_out, int out_size, void* d_ws, size_t ws_size,
                              hipStream_t stream) {
  const float* x      = (const float*)d_in[0];
  const int*   ei     = (const int*)d_in[1];
  const int*   batch  = (const int*)d_in[2];
  const float* W1     = (const float*)d_in[3];
  const float* a_src1 = (const float*)d_in[4];
  const float* a_dst1 = (const float*)d_in[5];
  const float* W2     = (const float*)d_in[6];
  const float* a_src2 = (const float*)d_in[7];
  const float* a_dst2 = (const float*)d_in[8];
  const float* bn1_g  = (const float*)d_in[9];
  const float* bn1_b  = (const float*)d_in[10];
  const float* bn2_g  = (const float*)d_in[11];
  const float* bn2_b  = (const float*)d_in[12];
  const float* cls_w1 = (const float*)d_in[13];
  const float* cls_b1 = (const float*)d_in[14];
  const float* cls_w2 = (const float*)d_in[15];
  const float* cls_b2 = (const float*)d_in[16];
  const float* ep_w1  = (const float*)d_in[17];
  const float* ep_b1  = (const float*)d_in[18];
  const float* ep_w2  = (const float*)d_in[19];
  const float* ep_b2  = (const float*)d_in[20];

  const int* srcp = ei;
  const int* dstp = ei + EE;

  // ---- workspace layout, byte offsets; total 79.82 MB ----
  char* base = (char*)d_ws;
  bf16*  h1   = (bf16*)(base);                 // (N,512) bf16: [0, 51.2e6)
  bf16*  Whh  = (bf16*)(base + 51200000);      // per-head (N,128) bf16
  float* Wh2  = (float*)(base + 51200000);     // layer2 (N,128) f32 (reuses Whh slot)
  float* es1  = (float*)(base + 76800000);
  float* ed1  = (float*)(base + 77000000);
  float* es2  = (float*)(base + 77200000);
  float* ed2  = (float*)(base + 77400000);
  float* stats = (float*)(base + 77600000);    // 3344 floats
  float* cs1 = stats,        *cq1 = stats + 512;
  float* cs2 = stats + 1024, *cq2 = stats + 1152;
  float* pooled = stats + 1280;                // 16*128
  float* cnt    = stats + 3328;                // 16
  int* deg    = (int*)(base + 77613376);       // N
  int* rowptr = (int*)(base + 77813376);       // N+1
  int* cursor = (int*)(base + 78013380);       // N
  int* csr    = (int*)(base + 78213380);       // E (ends at 79,813,380)
  // after layer 1 (h1 consumed by GEMM2), carve its region:
  bf16* h2p = (bf16*)(base);                   // (N,128) bf16
  bf16* h2  = (bf16*)(base + 12800000);        // (N,128) bf16
  bf16* P   = (bf16*)(base + 25600000);        // (N,128) bf16
  bf16* Q   = (bf16*)(base + 38400000);        // (N,128) bf16

  float* out        = (float*)d_out;
  float* out_logits = out;                          // 32
  float* out_h2     = out + 32;                     // N*128
  float* out_imp    = out + 32 + (size_t)NN * HID;  // E
  float* out_attn   = out_imp + EE;                 // E

  // zero accumulators (kernel, not memset — ws is poisoned 0xAA each call)
  zero_words<<<(NN + 255) / 256, 256, 0, stream>>>((unsigned int*)deg, NN);
  zero_words<<<(3344 + 255) / 256, 256, 0, stream>>>((unsigned int*)stats, 3344);

  // CSR by destination
  count_kernel<<<(EE + 255) / 256, 256, 0, stream>>>(dstp, deg, EE);
  scan_kernel<<<1, 1024, 0, stream>>>(deg, rowptr, cursor, NN);
  scatter_kernel<<<(EE + 255) / 256, 256, 0, stream>>>(dstp, cursor, csr, EE);

  // ---- layer 1, per head ----
  dim3 gh((HID + 63) / 64, (NN + 63) / 64);
  for (int h = 0; h < NH; ++h) {
    gemm_tiled<float, bf16><<<gh, 256, 0, stream>>>(x, W1 + (size_t)h * FIN * HID, Whh,
                                                    NN, FIN, HID);
    edot_kernel<bf16><<<(NN + 3) / 4, 256, 0, stream>>>(Whh, a_src1 + h * HID,
                                                        a_dst1 + h * HID, es1, ed1, NN);
    agg1h_kernel<<<(NN + 3) / 4, 256, 0, stream>>>(srcp, rowptr, csr, es1, ed1, Whh,
                                                   h1, h * HID);
  }

  elu_stats<<<200, C1, 0, stream>>>(h1, cs1, cq1, NN, C1);
  {
    size_t total = (size_t)NN * C1;
    bn_apply<<<(unsigned)((total + 255) / 256), 256, 0, stream>>>(
        h1, h1, (float*)nullptr, cs1, cq1, bn1_g, bn1_b, C1, total, 1.f / NN);
  }

  // ---- layer 2 ----
  gemm_tiled<bf16, float><<<gh, 256, 0, stream>>>(h1, W2, Wh2, NN, C1, HID);
  edot_kernel<float><<<(NN + 3) / 4, 256, 0, stream>>>(Wh2, a_src2, a_dst2, es2, ed2, NN);
  agg2_kernel<<<(NN + 3) / 4, 256, 0, stream>>>(srcp, rowptr, csr, es2, ed2, Wh2,
                                                h2p, out_attn);

  elu_stats<<<200, HID, 0, stream>>>(h2p, cs2, cq2, NN, HID);
  {
    size_t total = (size_t)NN * HID;
    bn_apply<<<(unsigned)((total + 255) / 256), 256, 0, stream>>>(
        h2p, h2, out_h2, cs2, cq2, bn2_g, bn2_b, HID, total, 1.f / NN);
  }

  // ---- heads: pool + classifier, edge importance ----
  pool_kernel<<<256, HID, 0, stream>>>(h2, batch, pooled, cnt);
  cls_kernel<<<1, 128, 0, stream>>>(pooled, cnt, cls_w1, cls_b1, cls_w2, cls_b2, out_logits);

  gemm_tiled<bf16, bf16><<<gh, 256, 0, stream>>>(h2, ep_w1, P, NN, HID, HID);
  gemm_tiled<bf16, bf16><<<gh, 256, 0, stream>>>(h2, ep_w1 + HID * HID, Q, NN, HID, HID);
  eimp_kernel<<<(EE + 3) / 4, 256, 0, stream>>>(srcp, dstp, P, Q, ep_b1, ep_w2, ep_b2, out_imp);
}

// Round 4
// 1555.429 us; speedup vs baseline: 1.3860x; 1.3860x over previous
//
#include <hip/hip_runtime.h>
#include <hip/hip_bf16.h>
#include <math.h>

typedef __hip_bfloat16 bf16;
typedef __bf16 bf16x8 __attribute__((ext_vector_type(8)));
typedef float f32x4 __attribute__((ext_vector_type(4)));

#define NN 50000
#define EE 400000
#define FIN 262
#define KP1 288   /* FIN padded to multiple of 32 */
#define HID 128
#define NH 4
#define C1 512   /* HID*NH */
#define NGR 16

__device__ __forceinline__ float b2f(bf16 x){ return __bfloat162float(x); }
__device__ __forceinline__ bf16 f2b(float x){ return __float2bfloat16(x); }
__device__ __forceinline__ float ldA(const bf16* p, size_t i){ return __bfloat162float(p[i]); }
__device__ __forceinline__ float ldA(const float* p, size_t i){ return p[i]; }

__global__ void zero_words(unsigned int* __restrict__ p, int n) {
  int i = blockIdx.x * 256 + threadIdx.x;
  if (i < n) p[i] = 0u;
}

// ================= MFMA GEMM: C(M,N) = A(M,K) @ B(K,N) =================
// A: (M,K) bf16 row-major; Bt: (N,K) bf16 row-major (pre-transposed B).
// K % 32 == 0, Ncols % 128 == 0. C: (M,N) bf16.
// Block 256 = 4 waves; 128x128 tile; wave w covers 64x64 at (w>>1, w&1).
__global__ __launch_bounds__(256)
void gemm_mfma(const bf16* __restrict__ A, const bf16* __restrict__ Bt,
               bf16* __restrict__ C, int M, int K, int Ncols) {
  __shared__ __align__(16) __bf16 As[128 * 40];  // +8 pad: 2-way banks only
  __shared__ __align__(16) __bf16 Bs[128 * 40];
  int bm = blockIdx.y * 128, bn = blockIdx.x * 128;
  int tid = threadIdx.x;
  int wave = tid >> 6, lane = tid & 63;
  int quad = lane >> 4, l16 = lane & 15;
  int wm = (wave >> 1) * 64, wn = (wave & 1) * 64;
  f32x4 acc[4][4];
  #pragma unroll
  for (int i = 0; i < 4; ++i)
    #pragma unroll
    for (int j = 0; j < 4; ++j)
      acc[i][j] = (f32x4){0.f, 0.f, 0.f, 0.f};

  for (int k0 = 0; k0 < K; k0 += 32) {
    #pragma unroll
    for (int l = 0; l < 2; ++l) {
      int e = l * 2048 + tid * 8;
      int row = e >> 5, col = e & 31;           // 128 rows x 32 cols
      uint4 va = {0u, 0u, 0u, 0u};
      int gm = bm + row;
      if (gm < M) va = *(const uint4*)(A + (size_t)gm * K + k0 + col);
      *(uint4*)(&As[row * 40 + col]) = va;
      uint4 vb = {0u, 0u, 0u, 0u};
      int gn = bn + row;
      if (gn < Ncols) vb = *(const uint4*)(Bt + (size_t)gn * K + k0 + col);
      *(uint4*)(&Bs[row * 40 + col]) = vb;
    }
    __syncthreads();
    bf16x8 af[4], bf_[4];
    #pragma unroll
    for (int i = 0; i < 4; ++i)
      af[i] = *(const bf16x8*)(&As[(wm + i * 16 + l16) * 40 + quad * 8]);
    #pragma unroll
    for (int j = 0; j < 4; ++j)
      bf_[j] = *(const bf16x8*)(&Bs[(wn + j * 16 + l16) * 40 + quad * 8]);
    #pragma unroll
    for (int i = 0; i < 4; ++i)
      #pragma unroll
      for (int j = 0; j < 4; ++j)
        acc[i][j] = __builtin_amdgcn_mfma_f32_16x16x32_bf16(af[i], bf_[j], acc[i][j], 0, 0, 0);
    __syncthreads();
  }
  // C/D layout: col = lane&15, row = quad*4 + r  [verified m89/m91]
  #pragma unroll
  for (int i = 0; i < 4; ++i) {
    #pragma unroll
    for (int r = 0; r < 4; ++r) {
      int gm = bm + wm + i * 16 + quad * 4 + r;
      if (gm >= M) continue;
      #pragma unroll
      for (int j = 0; j < 4; ++j) {
        int gn = bn + wn + j * 16 + l16;
        C[(size_t)gm * Ncols + gn] = f2b(acc[i][j][r]);
      }
    }
  }
}

// ---- prep: x (N,262) f32 -> xb (N,288) bf16 zero-padded ----
__global__ void conv_x(const float* __restrict__ x, bf16* __restrict__ xb) {
  int i = blockIdx.x * 256 + threadIdx.x;
  if (i >= NN * KP1) return;
  int row = i / KP1, col = i - row * KP1;
  xb[i] = (col < FIN) ? f2b(x[(size_t)row * FIN + col]) : f2b(0.f);
}
// ---- prep: W1 (H,262,128) f32 -> B1t (H*128, 288) bf16 (Bt layout per head) ----
__global__ void prep_b1t(const float* __restrict__ W1, bf16* __restrict__ B1t) {
  int i = blockIdx.x * 256 + threadIdx.x;
  if (i >= C1 * KP1) return;
  int n = i / KP1, k = i - n * KP1;   // n = h*128 + o
  int h = n >> 7, o = n & 127;
  B1t[i] = (k < FIN) ? f2b(W1[((size_t)h * FIN + k) * HID + o]) : f2b(0.f);
}
// ---- prep: W2 (512,128) f32 -> B2t (128,512) bf16 ----
__global__ void prep_b2t(const float* __restrict__ W2, bf16* __restrict__ B2t) {
  int i = blockIdx.x * 256 + threadIdx.x;
  if (i >= HID * C1) return;
  int n = i >> 9, k = i & 511;
  B2t[i] = f2b(W2[(size_t)k * HID + n]);
}
// ---- prep: ep_w1 (256,128) f32 -> BPt (256,128) bf16, n<128 => W_top col, else W_bot ----
__global__ void prep_bpt(const float* __restrict__ epw1, bf16* __restrict__ BPt) {
  int i = blockIdx.x * 256 + threadIdx.x;
  if (i >= 256 * HID) return;
  int n = i >> 7, k = i & 127;
  float v = (n < 128) ? epw1[(size_t)k * HID + n] : epw1[(size_t)(128 + k) * HID + (n - 128)];
  BPt[i] = f2b(v);
}

// per-node dot of Wh row (128 wide) with a_src/a_dst (f32); one wave per node
template<typename T>
__global__ void edot_kernel(const T* __restrict__ Wh, const float* __restrict__ av,
                            const float* __restrict__ bv, float* __restrict__ es,
                            float* __restrict__ ed, int n) {
  int wid = threadIdx.x >> 6, lane = threadIdx.x & 63;
  int r = blockIdx.x * 4 + wid;
  if (r >= n) return;
  const T* row = Wh + (size_t)r * HID;
  float w0 = ldA(row, lane), w1 = ldA(row, lane + 64);
  float s1 = w0 * av[lane] + w1 * av[lane + 64];
  float s2 = w0 * bv[lane] + w1 * bv[lane + 64];
  #pragma unroll
  for (int off = 32; off > 0; off >>= 1) {
    s1 += __shfl_xor(s1, off);
    s2 += __shfl_xor(s2, off);
  }
  if (lane == 0) { es[r] = s1; ed[r] = s2; }
}

// ---------------- CSR build (guarded) ----------------
__global__ void count_kernel(const int* __restrict__ dst, int* __restrict__ deg, int E) {
  int e = blockIdx.x * blockDim.x + threadIdx.x;
  if (e >= E) return;
  int d = dst[e];
  if ((unsigned)d < NN) atomicAdd(&deg[d], 1);
}

__global__ void scan_kernel(const int* __restrict__ deg, int* __restrict__ rowptr,
                            int* __restrict__ cursor, int n) {
  __shared__ int part[1024];
  int t = threadIdx.x;
  int chunk = (n + 1023) >> 10;
  int lo = t * chunk, hi = min(lo + chunk, n);
  int s = 0;
  for (int i = lo; i < hi; ++i) s += deg[i];
  part[t] = s;
  __syncthreads();
  if (t == 0) {
    int r = 0;
    for (int i = 0; i < 1024; ++i) { int v = part[i]; part[i] = r; r += v; }
  }
  __syncthreads();
  int r = part[t];
  for (int i = lo; i < hi; ++i) { rowptr[i] = r; cursor[i] = r; r += deg[i]; }
  if (lo < n && hi == n) rowptr[n] = r;
}

__global__ void scatter_kernel(const int* __restrict__ dst, int* __restrict__ cursor,
                               int* __restrict__ csr, int E) {
  int e = blockIdx.x * blockDim.x + threadIdx.x;
  if (e >= E) return;
  int d = dst[e];
  if ((unsigned)d >= NN) return;
  int p = atomicAdd(&cursor[d], 1);
  if ((unsigned)p < (unsigned)E) csr[p] = e;
}

// ---- layer-1, one head: edge softmax + aggregate; one wave per dst node ----
__global__ void agg1h_kernel(const int* __restrict__ src, const int* __restrict__ rowptr,
                             const int* __restrict__ csr,
                             const float* __restrict__ es, const float* __restrict__ edv,
                             const bf16* __restrict__ Whh, bf16* __restrict__ h1,
                             int coloff) {
  int wid = threadIdx.x >> 6, lane = threadIdx.x & 63;
  int node = blockIdx.x * 4 + wid;
  if (node >= NN) return;
  int b = rowptr[node], e = rowptr[node + 1];
  if (b < 0) b = 0; if (e > EE) e = EE;
  float ed = edv[node];
  float m = 0.f;  // e_max = max(seg_max, 0)
  for (int j = b; j < e; ++j) {
    int id = csr[j]; if ((unsigned)id >= EE) continue;
    int s = src[id]; if ((unsigned)s >= NN) s = 0;
    float v = es[s] + ed;
    v = v >= 0.f ? v : 0.2f * v;
    m = fmaxf(m, v);
  }
  float sum = 0.f, a0 = 0.f, a1 = 0.f;
  for (int j = b; j < e; ++j) {
    int id = csr[j]; if ((unsigned)id >= EE) continue;
    int s = src[id]; if ((unsigned)s >= NN) s = 0;
    float v = es[s] + ed;
    v = v >= 0.f ? v : 0.2f * v;
    float p = expf(v - m);
    sum += p;
    const bf16* wr = Whh + (size_t)s * HID;
    a0 += p * b2f(wr[lane]);
    a1 += p * b2f(wr[lane + 64]);
  }
  float scale = 1.f / (sum + 1e-8f);
  bf16* orow = h1 + (size_t)node * C1 + coloff;
  orow[lane] = f2b(a0 * scale);
  orow[lane + 64] = f2b(a1 * scale);
}

// ---- layer-2 (H=1): aggregate + attn output (f32) ----
__global__ void agg2_kernel(const int* __restrict__ src, const int* __restrict__ rowptr,
                            const int* __restrict__ csr,
                            const float* __restrict__ es, const float* __restrict__ edv,
                            const bf16* __restrict__ Wh, bf16* __restrict__ out,
                            float* __restrict__ attn_out) {
  int wid = threadIdx.x >> 6, lane = threadIdx.x & 63;
  int node = blockIdx.x * 4 + wid;
  if (node >= NN) return;
  int b = rowptr[node], e = rowptr[node + 1];
  if (b < 0) b = 0; if (e > EE) e = EE;
  float ed = edv[node];
  float m = 0.f;
  for (int j = b; j < e; ++j) {
    int id = csr[j]; if ((unsigned)id >= EE) continue;
    int s = src[id]; if ((unsigned)s >= NN) s = 0;
    float v = es[s] + ed;
    v = v >= 0.f ? v : 0.2f * v;
    m = fmaxf(m, v);
  }
  float sum = 0.f, a0 = 0.f, a1 = 0.f;
  for (int j = b; j < e; ++j) {
    int id = csr[j]; if ((unsigned)id >= EE) continue;
    int s = src[id]; if ((unsigned)s >= NN) s = 0;
    float v = es[s] + ed;
    v = v >= 0.f ? v : 0.2f * v;
    float p = expf(v - m);
    sum += p;
    a0 += p * b2f(Wh[(size_t)s * HID + lane]);
    a1 += p * b2f(Wh[(size_t)s * HID + lane + 64]);
  }
  float scale = 1.f / (sum + 1e-8f);
  out[(size_t)node * HID + lane] = f2b(a0 * scale);
  out[(size_t)node * HID + lane + 64] = f2b(a1 * scale);
  for (int j = b; j < e; ++j) {
    int id = csr[j]; if ((unsigned)id >= EE) continue;
    int s = src[id]; if ((unsigned)s >= NN) s = 0;
    float v = es[s] + ed;
    v = v >= 0.f ? v : 0.2f * v;
    if (lane == 0) attn_out[id] = expf(v - m) * scale;
  }
}

// ---- ELU in place (bf16) + per-column fp32 sum/sumsq; blockDim == C ----
__global__ void elu_stats(bf16* __restrict__ X, float* __restrict__ cs, float* __restrict__ cq,
                          int Nrows, int C) {
  int c = threadIdx.x;
  int rpb = (Nrows + gridDim.x - 1) / gridDim.x;
  int r0 = blockIdx.x * rpb, r1 = min(r0 + rpb, Nrows);
  float s = 0.f, s2 = 0.f;
  for (int r = r0; r < r1; ++r) {
    size_t idx = (size_t)r * C + c;
    float v = b2f(X[idx]);
    v = v > 0.f ? v : expm1f(v);
    X[idx] = f2b(v);
    s += v; s2 += v * v;
  }
  atomicAdd(&cs[c], s);
  atomicAdd(&cq[c], s2);
}

__global__ void bn_apply(const bf16* __restrict__ in, bf16* __restrict__ out,
                         float* __restrict__ out2,
                         const float* __restrict__ cs, const float* __restrict__ cq,
                         const float* __restrict__ gamma, const float* __restrict__ beta,
                         int C, size_t total, float invN) {
  size_t i = (size_t)blockIdx.x * blockDim.x + threadIdx.x;
  if (i >= total) return;
  int c = (int)(i % C);
  float mu = cs[c] * invN;
  float var = cq[c] * invN - mu * mu;
  float v = (b2f(in[i]) - mu) * rsqrtf(fmaxf(var, 0.f) + 1e-5f) * gamma[c] + beta[c];
  out[i] = f2b(v);
  if (out2) out2[i] = v;
}

// ---- global mean pool ----
__global__ void pool_kernel(const bf16* __restrict__ h2, const int* __restrict__ batch,
                            float* __restrict__ pooled, float* __restrict__ cnt) {
  __shared__ float acc[NGR * HID];
  __shared__ float ccnt[NGR];
  int f = threadIdx.x;  // 128 threads
  for (int i = f; i < NGR * HID; i += HID) acc[i] = 0.f;
  if (f < NGR) ccnt[f] = 0.f;
  __syncthreads();
  for (int r = blockIdx.x; r < NN; r += gridDim.x) {
    int g = batch[r]; if ((unsigned)g >= NGR) g = 0;
    acc[g * HID + f] += b2f(h2[(size_t)r * HID + f]);
    if (f == 0) ccnt[g] += 1.f;
  }
  __syncthreads();
  for (int i = f; i < NGR * HID; i += HID) atomicAdd(&pooled[i], acc[i]);
  if (f < NGR) atomicAdd(&cnt[f], ccnt[f]);
}

// ---- classifier (tiny, single block), f32 weights/out ----
__global__ void cls_kernel(const float* __restrict__ pooled, const float* __restrict__ cnt,
                           const float* __restrict__ w1, const float* __restrict__ b1,
                           const float* __restrict__ w2, const float* __restrict__ b2,
                           float* __restrict__ out) {
  __shared__ float repr[NGR * HID];
  __shared__ float hid[NGR * 64];
  int t = threadIdx.x;  // 128
  for (int i = t; i < NGR * HID; i += 128) {
    int g = i >> 7;
    repr[i] = pooled[i] / fmaxf(cnt[g], 1.f);
  }
  __syncthreads();
  for (int i = t; i < NGR * 64; i += 128) {
    int g = i >> 6, j = i & 63;
    float s = b1[j];
    for (int c = 0; c < HID; ++c) s += repr[g * HID + c] * w1[c * 64 + j];
    hid[i] = fmaxf(s, 0.f);
  }
  __syncthreads();
  if (t < NGR * 2) {
    int g = t >> 1, k = t & 1;
    float s = b2[k];
    for (int j = 0; j < 64; ++j) s += hid[g * 64 + j] * w2[j * 2 + k];
    out[t] = s;
  }
}

// ---- edge importance from fused PQ (N,256): relu(P[s]+Q[d]+b1)·w2+b2 → sigmoid ----
__global__ void eimp_kernel(const int* __restrict__ src, const int* __restrict__ dstp,
                            const bf16* __restrict__ PQ,
                            const float* __restrict__ b1, const float* __restrict__ w2,
                            const float* __restrict__ b2, float* __restrict__ out) {
  int wid = threadIdx.x >> 6, lane = threadIdx.x & 63;
  int e = blockIdx.x * 4 + wid;
  if (e >= EE) return;
  int s = src[e]; if ((unsigned)s >= NN) s = 0;
  int d = dstp[e]; if ((unsigned)d >= NN) d = 0;
  float acc = 0.f;
  #pragma unroll
  for (int r = 0; r < 2; ++r) {
    int j = lane + 64 * r;
    float h = b2f(PQ[(size_t)s * 256 + j]) + b2f(PQ[(size_t)d * 256 + 128 + j]) + b1[j];
    h = fmaxf(h, 0.f);
    acc += h * w2[j];
  }
  #pragma unroll
  for (int off = 32; off > 0; off >>= 1) acc += __shfl_xor(acc, off);
  if (lane == 0) {
    float z = acc + b2[0];
    out[e] = 1.f / (1.f + expf(-z));
  }
}

extern "C" void kernel_launch(void* const* d_in, const int* in_sizes, int n_in,
                              void* d_out, int out_size, void* d_ws, size_t ws_size,
                              hipStream_t stream) {
  const float* x      = (const float*)d_in[0];
  const int*   ei     = (const int*)d_in[1];
  const int*   batch  = (const int*)d_in[2];
  const float* W1     = (const float*)d_in[3];
  const float* a_src1 = (const float*)d_in[4];
  const float* a_dst1 = (const float*)d_in[5];
  const float* W2     = (const float*)d_in[6];
  const float* a_src2 = (const float*)d_in[7];
  const float* a_dst2 = (const float*)d_in[8];
  const float* bn1_g  = (const float*)d_in[9];
  const float* bn1_b  = (const float*)d_in[10];
  const float* bn2_g  = (const float*)d_in[11];
  const float* bn2_b  = (const float*)d_in[12];
  const float* cls_w1 = (const float*)d_in[13];
  const float* cls_b1 = (const float*)d_in[14];
  const float* cls_w2 = (const float*)d_in[15];
  const float* cls_b2 = (const float*)d_in[16];
  const float* ep_w1  = (const float*)d_in[17];
  const float* ep_b1  = (const float*)d_in[18];
  const float* ep_w2  = (const float*)d_in[19];
  const float* ep_b2  = (const float*)d_in[20];

  const int* srcp = ei;
  const int* dstp = ei + EE;

  // ---- workspace layout (bytes), peak ~96.3 MB, all 16B-aligned ----
  char* base = (char*)d_ws;
  bf16* xb   = (bf16*)(base);                  // (N,288) bf16: [0, 28.8M)
  bf16* h1   = (bf16*)(base + 28800000);       // (N,512) bf16: [28.8M, 80M)
  bf16* Whh  = (bf16*)(base + 80000000);       // per-head (N,128) bf16: [80M, 92.8M)
  bf16* Wh2  = (bf16*)(base + 80000000);       //   (reuses Whh slot after layer 1)
  bf16* h2p  = (bf16*)(base);                  // (N,128) bf16 (xb dead)
  bf16* h2   = (bf16*)(base + 12800000);       // (N,128) bf16 (xb dead)
  bf16* PQ   = (bf16*)(base + 28800000);       // (N,256) bf16 (h1 dead)
  float* es1 = (float*)(base + 92800000);
  float* ed1 = (float*)(base + 93000000);
  float* es2 = (float*)(base + 93200000);
  float* ed2 = (float*)(base + 93400000);
  float* stats = (float*)(base + 93600000);    // 3344 floats
  float* cs1 = stats,        *cq1 = stats + 512;
  float* cs2 = stats + 1024, *cq2 = stats + 1152;
  float* pooled = stats + 1280;                // 16*128
  float* cnt    = stats + 3328;                // 16
  int* deg    = (int*)(base + 93613376);       // N
  int* rowptr = (int*)(base + 93813376);       // N+1
  int* cursor = (int*)(base + 94013380);       // N
  int* csr    = (int*)(base + 94213380);       // E -> ends 95,813,380
  bf16* B1t   = (bf16*)(base + 95813392);      // (512,288) -> ends 96,108,304
  bf16* B2t   = (bf16*)(base + 96108304);      // (128,512) -> ends 96,239,376
  bf16* BPt   = (bf16*)(base + 96239376);      // (256,128) -> ends 96,304,912

  float* out        = (float*)d_out;
  float* out_logits = out;                          // 32
  float* out_h2     = out + 32;                     // N*128
  float* out_imp    = out + 32 + (size_t)NN * HID;  // E
  float* out_attn   = out_imp + EE;                 // E

  // zero accumulators (ws is poisoned 0xAA each call)
  zero_words<<<(NN + 255) / 256, 256, 0, stream>>>((unsigned int*)deg, NN);
  zero_words<<<(3344 + 255) / 256, 256, 0, stream>>>((unsigned int*)stats, 3344);

  // prep: bf16 conversions / transposes
  conv_x<<<(NN * KP1 + 255) / 256, 256, 0, stream>>>(x, xb);
  prep_b1t<<<(C1 * KP1 + 255) / 256, 256, 0, stream>>>(W1, B1t);
  prep_b2t<<<(HID * C1 + 255) / 256, 256, 0, stream>>>(W2, B2t);
  prep_bpt<<<(256 * HID + 255) / 256, 256, 0, stream>>>(ep_w1, BPt);

  // CSR by destination
  count_kernel<<<(EE + 255) / 256, 256, 0, stream>>>(dstp, deg, EE);
  scan_kernel<<<1, 1024, 0, stream>>>(deg, rowptr, cursor, NN);
  scatter_kernel<<<(EE + 255) / 256, 256, 0, stream>>>(dstp, cursor, csr, EE);

  // ---- layer 1, per head (MFMA GEMM + softmax-aggregate) ----
  dim3 g1(1, (NN + 127) / 128);
  for (int h = 0; h < NH; ++h) {
    gemm_mfma<<<g1, 256, 0, stream>>>(xb, B1t + (size_t)h * HID * KP1, Whh, NN, KP1, HID);
    edot_kernel<bf16><<<(NN + 3) / 4, 256, 0, stream>>>(Whh, a_src1 + h * HID,
                                                        a_dst1 + h * HID, es1, ed1, NN);
    agg1h_kernel<<<(NN + 3) / 4, 256, 0, stream>>>(srcp, rowptr, csr, es1, ed1, Whh,
                                                   h1, h * HID);
  }

  elu_stats<<<200, C1, 0, stream>>>(h1, cs1, cq1, NN, C1);
  {
    size_t total = (size_t)NN * C1;
    bn_apply<<<(unsigned)((total + 255) / 256), 256, 0, stream>>>(
        h1, h1, (float*)nullptr, cs1, cq1, bn1_g, bn1_b, C1, total, 1.f / NN);
  }

  // ---- layer 2 ----
  gemm_mfma<<<g1, 256, 0, stream>>>(h1, B2t, Wh2, NN, C1, HID);
  edot_kernel<bf16><<<(NN + 3) / 4, 256, 0, stream>>>(Wh2, a_src2, a_dst2, es2, ed2, NN);
  agg2_kernel<<<(NN + 3) / 4, 256, 0, stream>>>(srcp, rowptr, csr, es2, ed2, Wh2,
                                                h2p, out_attn);

  elu_stats<<<200, HID, 0, stream>>>(h2p, cs2, cq2, NN, HID);
  {
    size_t total = (size_t)NN * HID;
    bn_apply<<<(unsigned)((total + 255) / 256), 256, 0, stream>>>(
        h2p, h2, out_h2, cs2, cq2, bn2_g, bn2_b, HID, total, 1.f / NN);
  }

  // ---- heads: pool + classifier, fused edge-MLP GEMM, edge importance ----
  pool_kernel<<<256, HID, 0, stream>>>(h2, batch, pooled, cnt);
  cls_kernel<<<1, 128, 0, stream>>>(pooled, cnt, cls_w1, cls_b1, cls_w2, cls_b2, out_logits);

  dim3 gpq(2, (NN + 127) / 128);
  gemm_mfma<<<gpq, 256, 0, stream>>>(h2, BPt, PQ, NN, HID, 256);
  eimp_kernel<<<(EE + 3) / 4, 256, 0, stream>>>(srcp, dstp, PQ, ep_b1, ep_w2, ep_b2, out_imp);
}

// Round 5
// 1140.098 us; speedup vs baseline: 1.8909x; 1.3643x over previous
//
#include <hip/hip_runtime.h>
#include <hip/hip_bf16.h>
#include <math.h>

typedef __hip_bfloat16 bf16;
typedef __bf16 bf16x8 __attribute__((ext_vector_type(8)));
typedef __bf16 bf16x2v __attribute__((ext_vector_type(2)));
typedef float f32x4 __attribute__((ext_vector_type(4)));

#define NN 50000
#define EE 400000
#define FIN 262
#define KP1 288   /* FIN padded to multiple of 32 */
#define HID 128
#define NH 4
#define C1 512   /* HID*NH */
#define NGR 16

__device__ __forceinline__ float b2f(bf16 x){ return __bfloat162float(x); }
__device__ __forceinline__ bf16 f2b(float x){ return __float2bfloat16(x); }
__device__ __forceinline__ float ldA(const bf16* p, size_t i){ return __bfloat162float(p[i]); }
__device__ __forceinline__ float ldA(const float* p, size_t i){ return p[i]; }

__global__ void zero_words(unsigned int* __restrict__ p, int n) {
  int i = blockIdx.x * 256 + threadIdx.x;
  if (i < n) p[i] = 0u;
}

// ================= MFMA GEMM: C(M,N) = A(M,K) @ B(K,N) =================
// A: (M,K) bf16 row-major; Bt: (N,K) bf16 row-major (pre-transposed B).
// K % 32 == 0, Ncols % 128 == 0. C: (M,N) bf16.
__global__ __launch_bounds__(256)
void gemm_mfma(const bf16* __restrict__ A, const bf16* __restrict__ Bt,
               bf16* __restrict__ C, int M, int K, int Ncols) {
  __shared__ __align__(16) __bf16 As[128 * 40];  // +8 pad: 2-way banks only (free)
  __shared__ __align__(16) __bf16 Bs[128 * 40];
  int bm = blockIdx.y * 128, bn = blockIdx.x * 128;
  int tid = threadIdx.x;
  int wave = tid >> 6, lane = tid & 63;
  int quad = lane >> 4, l16 = lane & 15;
  int wm = (wave >> 1) * 64, wn = (wave & 1) * 64;
  f32x4 acc[4][4];
  #pragma unroll
  for (int i = 0; i < 4; ++i)
    #pragma unroll
    for (int j = 0; j < 4; ++j)
      acc[i][j] = (f32x4){0.f, 0.f, 0.f, 0.f};

  for (int k0 = 0; k0 < K; k0 += 32) {
    #pragma unroll
    for (int l = 0; l < 2; ++l) {
      int e = l * 2048 + tid * 8;
      int row = e >> 5, col = e & 31;           // 128 rows x 32 cols
      uint4 va = {0u, 0u, 0u, 0u};
      int gm = bm + row;
      if (gm < M) va = *(const uint4*)(A + (size_t)gm * K + k0 + col);
      *(uint4*)(&As[row * 40 + col]) = va;
      uint4 vb = {0u, 0u, 0u, 0u};
      int gn = bn + row;
      if (gn < Ncols) vb = *(const uint4*)(Bt + (size_t)gn * K + k0 + col);
      *(uint4*)(&Bs[row * 40 + col]) = vb;
    }
    __syncthreads();
    bf16x8 af[4], bf_[4];
    #pragma unroll
    for (int i = 0; i < 4; ++i)
      af[i] = *(const bf16x8*)(&As[(wm + i * 16 + l16) * 40 + quad * 8]);
    #pragma unroll
    for (int j = 0; j < 4; ++j)
      bf_[j] = *(const bf16x8*)(&Bs[(wn + j * 16 + l16) * 40 + quad * 8]);
    #pragma unroll
    for (int i = 0; i < 4; ++i)
      #pragma unroll
      for (int j = 0; j < 4; ++j)
        acc[i][j] = __builtin_amdgcn_mfma_f32_16x16x32_bf16(af[i], bf_[j], acc[i][j], 0, 0, 0);
    __syncthreads();
  }
  #pragma unroll
  for (int i = 0; i < 4; ++i) {
    #pragma unroll
    for (int r = 0; r < 4; ++r) {
      int gm = bm + wm + i * 16 + quad * 4 + r;
      if (gm >= M) continue;
      #pragma unroll
      for (int j = 0; j < 4; ++j) {
        int gn = bn + wn + j * 16 + l16;
        C[(size_t)gm * Ncols + gn] = f2b(acc[i][j][r]);
      }
    }
  }
}

// ---- prep kernels ----
__global__ void conv_x(const float* __restrict__ x, bf16* __restrict__ xb) {
  int i = blockIdx.x * 256 + threadIdx.x;
  if (i >= NN * KP1) return;
  int row = i / KP1, col = i - row * KP1;
  xb[i] = (col < FIN) ? f2b(x[(size_t)row * FIN + col]) : f2b(0.f);
}
__global__ void prep_b1t(const float* __restrict__ W1, bf16* __restrict__ B1t) {
  int i = blockIdx.x * 256 + threadIdx.x;
  if (i >= C1 * KP1) return;
  int n = i / KP1, k = i - n * KP1;   // n = h*128 + o
  int h = n >> 7, o = n & 127;
  B1t[i] = (k < FIN) ? f2b(W1[((size_t)h * FIN + k) * HID + o]) : f2b(0.f);
}
__global__ void prep_b2t(const float* __restrict__ W2, bf16* __restrict__ B2t) {
  int i = blockIdx.x * 256 + threadIdx.x;
  if (i >= HID * C1) return;
  int n = i >> 9, k = i & 511;
  B2t[i] = f2b(W2[(size_t)k * HID + n]);
}
__global__ void prep_bpt(const float* __restrict__ epw1, bf16* __restrict__ BPt) {
  int i = blockIdx.x * 256 + threadIdx.x;
  if (i >= 256 * HID) return;
  int n = i >> 7, k = i & 127;
  float v = (n < 128) ? epw1[(size_t)k * HID + n] : epw1[(size_t)(128 + k) * HID + (n - 128)];
  BPt[i] = f2b(v);
}

// ---- edot over all 4 heads: wave per node; lane: head = lane>>4, 8 feats ----
__global__ void edot_all(const bf16* __restrict__ Wh1, const float* __restrict__ av,
                         const float* __restrict__ bv, float* __restrict__ es1,
                         float* __restrict__ ed1) {
  int wid = threadIdx.x >> 6, lane = threadIdx.x & 63;
  int n = blockIdx.x * 4 + wid;
  if (n >= NN) return;
  int h = lane >> 4, c16 = lane & 15;
  int fbase = h * HID + c16 * 8;
  bf16x8 r = *(const bf16x8*)(Wh1 + (size_t)n * C1 + fbase);
  float s1 = 0.f, s2 = 0.f;
  #pragma unroll
  for (int j = 0; j < 8; ++j) {
    float rv = (float)r[j];
    s1 += rv * av[fbase + j];
    s2 += rv * bv[fbase + j];
  }
  #pragma unroll
  for (int off = 8; off > 0; off >>= 1) {
    s1 += __shfl_xor(s1, off);
    s2 += __shfl_xor(s2, off);
  }
  if (c16 == 0) { es1[n * 4 + h] = s1; ed1[n * 4 + h] = s2; }
}

// per-node dot (H=1, 128-wide); one wave per node
__global__ void edot1(const bf16* __restrict__ Wh, const float* __restrict__ av,
                      const float* __restrict__ bv, float* __restrict__ es,
                      float* __restrict__ ed) {
  int wid = threadIdx.x >> 6, lane = threadIdx.x & 63;
  int r = blockIdx.x * 4 + wid;
  if (r >= NN) return;
  const bf16* row = Wh + (size_t)r * HID;
  float w0 = b2f(row[lane]), w1 = b2f(row[lane + 64]);
  float s1 = w0 * av[lane] + w1 * av[lane + 64];
  float s2 = w0 * bv[lane] + w1 * bv[lane + 64];
  #pragma unroll
  for (int off = 32; off > 0; off >>= 1) {
    s1 += __shfl_xor(s1, off);
    s2 += __shfl_xor(s2, off);
  }
  if (lane == 0) { es[r] = s1; ed[r] = s2; }
}

// ---------------- CSR build ----------------
__global__ void count_kernel(const int* __restrict__ dst, int* __restrict__ deg, int E) {
  int e = blockIdx.x * blockDim.x + threadIdx.x;
  if (e >= E) return;
  int d = dst[e];
  if ((unsigned)d < NN) atomicAdd(&deg[d], 1);
}

__global__ void scan_kernel(const int* __restrict__ deg, int* __restrict__ rowptr,
                            int* __restrict__ cursor, int n) {
  __shared__ int part[1024];
  int t = threadIdx.x;
  int chunk = (n + 1023) >> 10;
  int lo = t * chunk, hi = min(lo + chunk, n);
  int s = 0;
  for (int i = lo; i < hi; ++i) s += deg[i];
  part[t] = s;
  __syncthreads();
  if (t == 0) {
    int r = 0;
    for (int i = 0; i < 1024; ++i) { int v = part[i]; part[i] = r; r += v; }
  }
  __syncthreads();
  int r = part[t];
  for (int i = lo; i < hi; ++i) { rowptr[i] = r; cursor[i] = r; r += deg[i]; }
  if (lo < n && hi == n) rowptr[n] = r;
}

// csr entry = {edge id, src node}
__global__ void scatter_kernel(const int* __restrict__ src, const int* __restrict__ dst,
                               int* __restrict__ cursor, int2* __restrict__ csr2, int E) {
  int e = blockIdx.x * blockDim.x + threadIdx.x;
  if (e >= E) return;
  int d = dst[e];
  if ((unsigned)d >= NN) return;
  int s = src[e]; if ((unsigned)s >= NN) s = 0;
  int p = atomicAdd(&cursor[d], 1);
  if ((unsigned)p < (unsigned)E) csr2[p] = make_int2(e, s);
}

// ---- layer-1 edge logits (4 heads) + atomic max per dst ----
__global__ void elog1(const int* __restrict__ src, const int* __restrict__ dst,
                      const float4* __restrict__ es1, const float4* __restrict__ ed1,
                      float4* __restrict__ evalw, unsigned* __restrict__ m1) {
  int e = blockIdx.x * 256 + threadIdx.x;
  if (e >= EE) return;
  int s = src[e]; if ((unsigned)s >= NN) s = 0;
  int d = dst[e]; if ((unsigned)d >= NN) d = 0;
  float4 a = es1[s], b = ed1[d];
  float v[4] = {a.x + b.x, a.y + b.y, a.z + b.z, a.w + b.w};
  #pragma unroll
  for (int h = 0; h < 4; ++h) v[h] = v[h] >= 0.f ? v[h] : 0.2f * v[h];
  evalw[e] = make_float4(v[0], v[1], v[2], v[3]);
  #pragma unroll
  for (int h = 0; h < 4; ++h)
    atomicMax(m1 + d * 4 + h, __float_as_uint(fmaxf(v[h], 0.f)));
}

// ---- layer-1 edge weights: w = exp(v - m[dst]) in-place + atomic sum ----
__global__ void ewei1(const int* __restrict__ dst, float4* __restrict__ evalw,
                      const unsigned* __restrict__ m1, float* __restrict__ sum1) {
  int e = blockIdx.x * 256 + threadIdx.x;
  if (e >= EE) return;
  int d = dst[e]; if ((unsigned)d >= NN) d = 0;
  float4 v = evalw[e];
  const unsigned* mp = m1 + d * 4;
  float w0 = expf(v.x - __uint_as_float(mp[0]));
  float w1 = expf(v.y - __uint_as_float(mp[1]));
  float w2 = expf(v.z - __uint_as_float(mp[2]));
  float w3 = expf(v.w - __uint_as_float(mp[3]));
  evalw[e] = make_float4(w0, w1, w2, w3);
  atomicAdd(sum1 + d * 4 + 0, w0);
  atomicAdd(sum1 + d * 4 + 1, w1);
  atomicAdd(sum1 + d * 4 + 2, w2);
  atomicAdd(sum1 + d * 4 + 3, w3);
}

// ---- layer-1 aggregate, all heads: wave per node, 8 feats/lane ----
__global__ __launch_bounds__(256)
void agg1_all(const int2* __restrict__ csr2, const int* __restrict__ rowptr,
              const float4* __restrict__ w4arr, const float* __restrict__ sum1,
              const bf16* __restrict__ Wh1, bf16* __restrict__ h1) {
  int wid = threadIdx.x >> 6, lane = threadIdx.x & 63;
  int node = blockIdx.x * 4 + wid;
  if (node >= NN) return;
  int b = rowptr[node], e = rowptr[node + 1];
  if (b < 0) b = 0; if (e > EE) e = EE;
  int h = lane >> 4;
  float acc[8] = {};
  for (int j = b; j < e; ++j) {
    int2 c = csr2[j];
    float4 w4 = w4arr[c.x];
    float wv = h == 0 ? w4.x : h == 1 ? w4.y : h == 2 ? w4.z : w4.w;
    bf16x8 r = *(const bf16x8*)(Wh1 + (size_t)c.y * C1 + lane * 8);
    #pragma unroll
    for (int k = 0; k < 8; ++k) acc[k] += wv * (float)r[k];
  }
  float scale = 1.f / (sum1[node * 4 + h] + 1e-8f);
  bf16x8 o;
  #pragma unroll
  for (int k = 0; k < 8; ++k) o[k] = (__bf16)(acc[k] * scale);
  *(bf16x8*)(h1 + (size_t)node * C1 + lane * 8) = o;
}

// ---- layer-2 edge logits/weights (H=1) ----
__global__ void elog2(const int* __restrict__ src, const int* __restrict__ dst,
                      const float* __restrict__ es2, const float* __restrict__ ed2,
                      float* __restrict__ w2e, unsigned* __restrict__ m2) {
  int e = blockIdx.x * 256 + threadIdx.x;
  if (e >= EE) return;
  int s = src[e]; if ((unsigned)s >= NN) s = 0;
  int d = dst[e]; if ((unsigned)d >= NN) d = 0;
  float v = es2[s] + ed2[d];
  v = v >= 0.f ? v : 0.2f * v;
  w2e[e] = v;
  atomicMax(m2 + d, __float_as_uint(fmaxf(v, 0.f)));
}
__global__ void ewei2(const int* __restrict__ dst, float* __restrict__ w2e,
                      const unsigned* __restrict__ m2, float* __restrict__ sum2) {
  int e = blockIdx.x * 256 + threadIdx.x;
  if (e >= EE) return;
  int d = dst[e]; if ((unsigned)d >= NN) d = 0;
  float w = expf(w2e[e] - __uint_as_float(m2[d]));
  w2e[e] = w;
  atomicAdd(sum2 + d, w);
}

// ---- layer-2 aggregate: wave per node, 2 feats/lane ----
__global__ __launch_bounds__(256)
void agg2_all(const int2* __restrict__ csr2, const int* __restrict__ rowptr,
              const float* __restrict__ w2e, const float* __restrict__ sum2,
              const bf16* __restrict__ Wh2, bf16* __restrict__ h2p,
              float* __restrict__ invs2) {
  int wid = threadIdx.x >> 6, lane = threadIdx.x & 63;
  int node = blockIdx.x * 4 + wid;
  if (node >= NN) return;
  int b = rowptr[node], e = rowptr[node + 1];
  if (b < 0) b = 0; if (e > EE) e = EE;
  float a0 = 0.f, a1 = 0.f;
  for (int j = b; j < e; ++j) {
    int2 c = csr2[j];
    float w = w2e[c.x];
    bf16x2v r = *(const bf16x2v*)(Wh2 + (size_t)c.y * HID + lane * 2);
    a0 += w * (float)r[0];
    a1 += w * (float)r[1];
  }
  float scale = 1.f / (sum2[node] + 1e-8f);
  bf16x2v o;
  o[0] = (__bf16)(a0 * scale);
  o[1] = (__bf16)(a1 * scale);
  *(bf16x2v*)(h2p + (size_t)node * HID + lane * 2) = o;
  if (lane == 0) invs2[node] = scale;
}

// ---- attention output (edge-parallel) ----
__global__ void attn_edge(const int* __restrict__ dst, const float* __restrict__ w2e,
                          const float* __restrict__ invs2, float* __restrict__ attn_out) {
  int e = blockIdx.x * 256 + threadIdx.x;
  if (e >= EE) return;
  int d = dst[e]; if ((unsigned)d >= NN) d = 0;
  attn_out[e] = w2e[e] * invs2[d];
}

// ---- ELU in place (bf16) + per-column fp32 sum/sumsq; blockDim == C ----
__global__ void elu_stats(bf16* __restrict__ X, float* __restrict__ cs, float* __restrict__ cq,
                          int Nrows, int C) {
  int c = threadIdx.x;
  int rpb = (Nrows + gridDim.x - 1) / gridDim.x;
  int r0 = blockIdx.x * rpb, r1 = min(r0 + rpb, Nrows);
  float s = 0.f, s2 = 0.f;
  for (int r = r0; r < r1; ++r) {
    size_t idx = (size_t)r * C + c;
    float v = b2f(X[idx]);
    v = v > 0.f ? v : expm1f(v);
    X[idx] = f2b(v);
    s += v; s2 += v * v;
  }
  atomicAdd(&cs[c], s);
  atomicAdd(&cq[c], s2);
}

__global__ void bn_apply(const bf16* __restrict__ in, bf16* __restrict__ out,
                         float* __restrict__ out2,
                         const float* __restrict__ cs, const float* __restrict__ cq,
                         const float* __restrict__ gamma, const float* __restrict__ beta,
                         int C, size_t total, float invN) {
  size_t i = (size_t)blockIdx.x * blockDim.x + threadIdx.x;
  if (i >= total) return;
  int c = (int)(i % C);
  float mu = cs[c] * invN;
  float var = cq[c] * invN - mu * mu;
  float v = (b2f(in[i]) - mu) * rsqrtf(fmaxf(var, 0.f) + 1e-5f) * gamma[c] + beta[c];
  out[i] = f2b(v);
  if (out2) out2[i] = v;
}

// ---- global mean pool ----
__global__ void pool_kernel(const bf16* __restrict__ h2, const int* __restrict__ batch,
                            float* __restrict__ pooled, float* __restrict__ cnt) {
  __shared__ float acc[NGR * HID];
  __shared__ float ccnt[NGR];
  int f = threadIdx.x;  // 128 threads
  for (int i = f; i < NGR * HID; i += HID) acc[i] = 0.f;
  if (f < NGR) ccnt[f] = 0.f;
  __syncthreads();
  for (int r = blockIdx.x; r < NN; r += gridDim.x) {
    int g = batch[r]; if ((unsigned)g >= NGR) g = 0;
    acc[g * HID + f] += b2f(h2[(size_t)r * HID + f]);
    if (f == 0) ccnt[g] += 1.f;
  }
  __syncthreads();
  for (int i = f; i < NGR * HID; i += HID) atomicAdd(&pooled[i], acc[i]);
  if (f < NGR) atomicAdd(&cnt[f], ccnt[f]);
}

// ---- classifier (tiny, single block) ----
__global__ void cls_kernel(const float* __restrict__ pooled, const float* __restrict__ cnt,
                           const float* __restrict__ w1, const float* __restrict__ b1,
                           const float* __restrict__ w2, const float* __restrict__ b2,
                           float* __restrict__ out) {
  __shared__ float repr[NGR * HID];
  __shared__ float hid[NGR * 64];
  int t = threadIdx.x;  // 128
  for (int i = t; i < NGR * HID; i += 128) {
    int g = i >> 7;
    repr[i] = pooled[i] / fmaxf(cnt[g], 1.f);
  }
  __syncthreads();
  for (int i = t; i < NGR * 64; i += 128) {
    int g = i >> 6, j = i & 63;
    float s = b1[j];
    for (int c = 0; c < HID; ++c) s += repr[g * HID + c] * w1[c * 64 + j];
    hid[i] = fmaxf(s, 0.f);
  }
  __syncthreads();
  if (t < NGR * 2) {
    int g = t >> 1, k = t & 1;
    float s = b2[k];
    for (int j = 0; j < 64; ++j) s += hid[g * 64 + j] * w2[j * 2 + k];
    out[t] = s;
  }
}

// ---- edge importance from fused PQ (N,256) ----
__global__ void eimp_kernel(const int* __restrict__ src, const int* __restrict__ dstp,
                            const bf16* __restrict__ PQ,
                            const float* __restrict__ b1, const float* __restrict__ w2,
                            const float* __restrict__ b2, float* __restrict__ out) {
  int wid = threadIdx.x >> 6, lane = threadIdx.x & 63;
  int e = blockIdx.x * 4 + wid;
  if (e >= EE) return;
  int s = src[e]; if ((unsigned)s >= NN) s = 0;
  int d = dstp[e]; if ((unsigned)d >= NN) d = 0;
  bf16x2v p2 = *(const bf16x2v*)(PQ + (size_t)s * 256 + lane * 2);
  bf16x2v q2 = *(const bf16x2v*)(PQ + (size_t)d * 256 + 128 + lane * 2);
  float acc = 0.f;
  #pragma unroll
  for (int r = 0; r < 2; ++r) {
    int j = lane * 2 + r;
    float hh = (float)p2[r] + (float)q2[r] + b1[j];
    hh = fmaxf(hh, 0.f);
    acc += hh * w2[j];
  }
  #pragma unroll
  for (int off = 32; off > 0; off >>= 1) acc += __shfl_xor(acc, off);
  if (lane == 0) {
    float z = acc + b2[0];
    out[e] = 1.f / (1.f + expf(-z));
  }
}

extern "C" void kernel_launch(void* const* d_in, const int* in_sizes, int n_in,
                              void* d_out, int out_size, void* d_ws, size_t ws_size,
                              hipStream_t stream) {
  const float* x      = (const float*)d_in[0];
  const int*   ei     = (const int*)d_in[1];
  const int*   batch  = (const int*)d_in[2];
  const float* W1     = (const float*)d_in[3];
  const float* a_src1 = (const float*)d_in[4];
  const float* a_dst1 = (const float*)d_in[5];
  const float* W2     = (const float*)d_in[6];
  const float* a_src2 = (const float*)d_in[7];
  const float* a_dst2 = (const float*)d_in[8];
  const float* bn1_g  = (const float*)d_in[9];
  const float* bn1_b  = (const float*)d_in[10];
  const float* bn2_g  = (const float*)d_in[11];
  const float* bn2_b  = (const float*)d_in[12];
  const float* cls_w1 = (const float*)d_in[13];
  const float* cls_b1 = (const float*)d_in[14];
  const float* cls_w2 = (const float*)d_in[15];
  const float* cls_b2 = (const float*)d_in[16];
  const float* ep_w1  = (const float*)d_in[17];
  const float* ep_b1  = (const float*)d_in[18];
  const float* ep_w2  = (const float*)d_in[19];
  const float* ep_b2  = (const float*)d_in[20];

  const int* srcp = ei;
  const int* dstp = ei + EE;

  // ---- workspace layout (bytes), peak ~118.9 MB, hazard-checked ----
  char* base = (char*)d_ws;
  // region A [0, 51.2e6): xb first (28.8e6), then h1 (51.2e6) — xb dead before agg1 writes h1
  bf16* xb  = (bf16*)(base);
  bf16* h1  = (bf16*)(base);
  // region B [51.2e6, 102.4e6): Wh1; later Wh2/h2p/h2; later PQ over dead Wh2+h2p
  bf16* Wh1 = (bf16*)(base + 51200000);
  bf16* Wh2 = (bf16*)(base + 51200000);   // (N,128) after agg1 (Wh1 dead)
  bf16* h2p = (bf16*)(base + 64000000);   // (N,128)
  bf16* h2  = (bf16*)(base + 76800000);   // (N,128)
  bf16* PQ  = (bf16*)(base + 51200000);   // (N,256) after bn2 (Wh2,h2p dead)
  // region S [102.4e6, ...): small buffers; first chunk is zeroed in one call
  unsigned* m1  = (unsigned*)(base + 102400000);  // (N,4)
  float* sum1   = (float*)(base + 103200000);     // (N,4)
  unsigned* m2  = (unsigned*)(base + 104000000);  // (N)
  float* sum2   = (float*)(base + 104200000);     // (N)
  int* deg      = (int*)(base + 104400000);       // (N)
  float* stats  = (float*)(base + 104600000);     // 3344 floats
  //   zero range = [102400000, 104613376) = 553,344 words
  float* cs1 = stats,        *cq1 = stats + 512;
  float* cs2 = stats + 1024, *cq2 = stats + 1152;
  float* pooled = stats + 1280;                   // 16*128
  float* cnt    = stats + 3328;                   // 16
  float* es1    = (float*)(base + 104613376);     // (N,4)
  float* ed1    = (float*)(base + 105413376);     // (N,4)
  float* evalw  = (float*)(base + 106213376);     // (E,4) logits -> weights
  float* es2    = (float*)(base + 112613376);     // (N)
  float* ed2    = (float*)(base + 112813376);     // (N)
  float* w2e    = (float*)(base + 113013376);     // (E)
  float* invs2  = (float*)(base + 114613376);     // (N)
  int* rowptr   = (int*)(base + 114813376);       // (N+1)
  int* cursor   = (int*)(base + 115013380);       // (N)
  int2* csr2    = (int2*)(base + 115213384);      // (E) {edge, src}
  bf16* B1t     = (bf16*)(base + 118413392);      // (512,288)
  bf16* B2t     = (bf16*)(base + 118708304);      // (128,512)
  bf16* BPt     = (bf16*)(base + 118839376);      // (256,128) -> ends 118,904,912

  float* out        = (float*)d_out;
  float* out_logits = out;                          // 32
  float* out_h2     = out + 32;                     // N*128
  float* out_imp    = out + 32 + (size_t)NN * HID;  // E
  float* out_attn   = out_imp + EE;                 // E

  // zero m1/sum1/m2/sum2/deg/stats in one call (ws poisoned 0xAA each call)
  zero_words<<<(553344 + 255) / 256, 256, 0, stream>>>((unsigned int*)m1, 553344);

  // prep: bf16 conversions / transposes
  conv_x<<<(NN * KP1 + 255) / 256, 256, 0, stream>>>(x, xb);
  prep_b1t<<<(C1 * KP1 + 255) / 256, 256, 0, stream>>>(W1, B1t);
  prep_b2t<<<(HID * C1 + 255) / 256, 256, 0, stream>>>(W2, B2t);
  prep_bpt<<<(256 * HID + 255) / 256, 256, 0, stream>>>(ep_w1, BPt);

  // CSR by destination (entries carry {edge, src})
  count_kernel<<<(EE + 255) / 256, 256, 0, stream>>>(dstp, deg, EE);
  scan_kernel<<<1, 1024, 0, stream>>>(deg, rowptr, cursor, NN);
  scatter_kernel<<<(EE + 255) / 256, 256, 0, stream>>>(srcp, dstp, cursor, csr2, EE);

  // ---- layer 1: one GEMM (all heads), edge-parallel softmax, one aggregate ----
  dim3 g1(C1 / 128, (NN + 127) / 128);
  gemm_mfma<<<g1, 256, 0, stream>>>(xb, B1t, Wh1, NN, KP1, C1);
  edot_all<<<(NN + 3) / 4, 256, 0, stream>>>(Wh1, a_src1, a_dst1, es1, ed1);
  elog1<<<(EE + 255) / 256, 256, 0, stream>>>(srcp, dstp, (const float4*)es1,
                                              (const float4*)ed1, (float4*)evalw, m1);
  ewei1<<<(EE + 255) / 256, 256, 0, stream>>>(dstp, (float4*)evalw, m1, sum1);
  agg1_all<<<(NN + 3) / 4, 256, 0, stream>>>(csr2, rowptr, (const float4*)evalw, sum1,
                                             Wh1, h1);

  elu_stats<<<400, C1, 0, stream>>>(h1, cs1, cq1, NN, C1);
  {
    size_t total = (size_t)NN * C1;
    bn_apply<<<(unsigned)((total + 255) / 256), 256, 0, stream>>>(
        h1, h1, (float*)nullptr, cs1, cq1, bn1_g, bn1_b, C1, total, 1.f / NN);
  }

  // ---- layer 2 ----
  dim3 g2(1, (NN + 127) / 128);
  gemm_mfma<<<g2, 256, 0, stream>>>(h1, B2t, Wh2, NN, C1, HID);
  edot1<<<(NN + 3) / 4, 256, 0, stream>>>(Wh2, a_src2, a_dst2, es2, ed2);
  elog2<<<(EE + 255) / 256, 256, 0, stream>>>(srcp, dstp, es2, ed2, w2e, m2);
  ewei2<<<(EE + 255) / 256, 256, 0, stream>>>(dstp, w2e, m2, sum2);
  agg2_all<<<(NN + 3) / 4, 256, 0, stream>>>(csr2, rowptr, w2e, sum2, Wh2, h2p, invs2);
  attn_edge<<<(EE + 255) / 256, 256, 0, stream>>>(dstp, w2e, invs2, out_attn);

  elu_stats<<<400, HID, 0, stream>>>(h2p, cs2, cq2, NN, HID);
  {
    size_t total = (size_t)NN * HID;
    bn_apply<<<(unsigned)((total + 255) / 256), 256, 0, stream>>>(
        h2p, h2, out_h2, cs2, cq2, bn2_g, bn2_b, HID, total, 1.f / NN);
  }

  // ---- heads ----
  pool_kernel<<<256, HID, 0, stream>>>(h2, batch, pooled, cnt);
  cls_kernel<<<1, 128, 0, stream>>>(pooled, cnt, cls_w1, cls_b1, cls_w2, cls_b2, out_logits);

  dim3 gpq(2, (NN + 127) / 128);
  gemm_mfma<<<gpq, 256, 0, stream>>>(h2, BPt, PQ, NN, HID, 256);
  eimp_kernel<<<(EE + 3) / 4, 256, 0, stream>>>(srcp, dstp, PQ, ep_b1, ep_w2, ep_b2, out_imp);
}

// Round 6
// 1035.382 us; speedup vs baseline: 2.0822x; 1.1011x over previous
//
#include <hip/hip_runtime.h>
#include <hip/hip_bf16.h>
#include <math.h>

typedef __hip_bfloat16 bf16;
typedef __bf16 bf16x8 __attribute__((ext_vector_type(8)));
typedef __bf16 bf16x2v __attribute__((ext_vector_type(2)));
typedef float f32x4 __attribute__((ext_vector_type(4)));

#define NN 50000
#define EE 400000
#define FIN 262
#define KP1 288   /* FIN padded to multiple of 32 */
#define HID 128
#define NH 4
#define C1 512   /* HID*NH */
#define NGR 16
#define SCAN_NB ((NN + 255) / 256)   /* 196 */

__device__ __forceinline__ float b2f(bf16 x){ return __bfloat162float(x); }
__device__ __forceinline__ bf16 f2b(float x){ return __float2bfloat16(x); }

__global__ void zero_words(unsigned int* __restrict__ p, int n) {
  int i = blockIdx.x * 256 + threadIdx.x;
  if (i < n) p[i] = 0u;
}

// ================= MFMA GEMM: C(M,N) = A(M,K) @ B(K,N) =================
// A: (M,K) bf16 row-major; Bt: (N,K) bf16 row-major (pre-transposed B).
// K % 32 == 0, Ncols % 128 == 0. C: (M,N) bf16.
__global__ __launch_bounds__(256)
void gemm_mfma(const bf16* __restrict__ A, const bf16* __restrict__ Bt,
               bf16* __restrict__ C, int M, int K, int Ncols) {
  __shared__ __align__(16) __bf16 As[128 * 40];  // +8 pad: 2-way banks only (free)
  __shared__ __align__(16) __bf16 Bs[128 * 40];
  int bm = blockIdx.y * 128, bn = blockIdx.x * 128;
  int tid = threadIdx.x;
  int wave = tid >> 6, lane = tid & 63;
  int quad = lane >> 4, l16 = lane & 15;
  int wm = (wave >> 1) * 64, wn = (wave & 1) * 64;
  f32x4 acc[4][4];
  #pragma unroll
  for (int i = 0; i < 4; ++i)
    #pragma unroll
    for (int j = 0; j < 4; ++j)
      acc[i][j] = (f32x4){0.f, 0.f, 0.f, 0.f};

  for (int k0 = 0; k0 < K; k0 += 32) {
    #pragma unroll
    for (int l = 0; l < 2; ++l) {
      int e = l * 2048 + tid * 8;
      int row = e >> 5, col = e & 31;           // 128 rows x 32 cols
      uint4 va = {0u, 0u, 0u, 0u};
      int gm = bm + row;
      if (gm < M) va = *(const uint4*)(A + (size_t)gm * K + k0 + col);
      *(uint4*)(&As[row * 40 + col]) = va;
      uint4 vb = {0u, 0u, 0u, 0u};
      int gn = bn + row;
      if (gn < Ncols) vb = *(const uint4*)(Bt + (size_t)gn * K + k0 + col);
      *(uint4*)(&Bs[row * 40 + col]) = vb;
    }
    __syncthreads();
    bf16x8 af[4], bf_[4];
    #pragma unroll
    for (int i = 0; i < 4; ++i)
      af[i] = *(const bf16x8*)(&As[(wm + i * 16 + l16) * 40 + quad * 8]);
    #pragma unroll
    for (int j = 0; j < 4; ++j)
      bf_[j] = *(const bf16x8*)(&Bs[(wn + j * 16 + l16) * 40 + quad * 8]);
    #pragma unroll
    for (int i = 0; i < 4; ++i)
      #pragma unroll
      for (int j = 0; j < 4; ++j)
        acc[i][j] = __builtin_amdgcn_mfma_f32_16x16x32_bf16(af[i], bf_[j], acc[i][j], 0, 0, 0);
    __syncthreads();
  }
  #pragma unroll
  for (int i = 0; i < 4; ++i) {
    #pragma unroll
    for (int r = 0; r < 4; ++r) {
      int gm = bm + wm + i * 16 + quad * 4 + r;
      if (gm >= M) continue;
      #pragma unroll
      for (int j = 0; j < 4; ++j) {
        int gn = bn + wn + j * 16 + l16;
        C[(size_t)gm * Ncols + gn] = f2b(acc[i][j][r]);
      }
    }
  }
}

// ---- prep kernels ----
__global__ void conv_x(const float* __restrict__ x, bf16* __restrict__ xb) {
  int i = blockIdx.x * 256 + threadIdx.x;
  if (i >= NN * KP1) return;
  int row = i / KP1, col = i - row * KP1;
  xb[i] = (col < FIN) ? f2b(x[(size_t)row * FIN + col]) : f2b(0.f);
}
__global__ void prep_b1t(const float* __restrict__ W1, bf16* __restrict__ B1t) {
  int i = blockIdx.x * 256 + threadIdx.x;
  if (i >= C1 * KP1) return;
  int n = i / KP1, k = i - n * KP1;   // n = h*128 + o
  int h = n >> 7, o = n & 127;
  B1t[i] = (k < FIN) ? f2b(W1[((size_t)h * FIN + k) * HID + o]) : f2b(0.f);
}
__global__ void prep_b2t(const float* __restrict__ W2, bf16* __restrict__ B2t) {
  int i = blockIdx.x * 256 + threadIdx.x;
  if (i >= HID * C1) return;
  int n = i >> 9, k = i & 511;
  B2t[i] = f2b(W2[(size_t)k * HID + n]);
}
__global__ void prep_bpt(const float* __restrict__ epw1, bf16* __restrict__ BPt) {
  int i = blockIdx.x * 256 + threadIdx.x;
  if (i >= 256 * HID) return;
  int n = i >> 7, k = i & 127;
  float v = (n < 128) ? epw1[(size_t)k * HID + n] : epw1[(size_t)(128 + k) * HID + (n - 128)];
  BPt[i] = f2b(v);
}

// ---- edot over all 4 heads: wave per node; lane: head = lane>>4, 8 feats ----
__global__ void edot_all(const bf16* __restrict__ Wh1, const float* __restrict__ av,
                         const float* __restrict__ bv, float* __restrict__ es1,
                         float* __restrict__ ed1) {
  int wid = threadIdx.x >> 6, lane = threadIdx.x & 63;
  int n = blockIdx.x * 4 + wid;
  if (n >= NN) return;
  int h = lane >> 4, c16 = lane & 15;
  int fbase = h * HID + c16 * 8;
  bf16x8 r = *(const bf16x8*)(Wh1 + (size_t)n * C1 + fbase);
  float s1 = 0.f, s2 = 0.f;
  #pragma unroll
  for (int j = 0; j < 8; ++j) {
    float rv = (float)r[j];
    s1 += rv * av[fbase + j];
    s2 += rv * bv[fbase + j];
  }
  #pragma unroll
  for (int off = 8; off > 0; off >>= 1) {
    s1 += __shfl_xor(s1, off);
    s2 += __shfl_xor(s2, off);
  }
  if (c16 == 0) { es1[n * 4 + h] = s1; ed1[n * 4 + h] = s2; }
}

// per-node dot (H=1, 128-wide); one wave per node
__global__ void edot1(const bf16* __restrict__ Wh, const float* __restrict__ av,
                      const float* __restrict__ bv, float* __restrict__ es,
                      float* __restrict__ ed) {
  int wid = threadIdx.x >> 6, lane = threadIdx.x & 63;
  int r = blockIdx.x * 4 + wid;
  if (r >= NN) return;
  const bf16* row = Wh + (size_t)r * HID;
  float w0 = b2f(row[lane]), w1 = b2f(row[lane + 64]);
  float s1 = w0 * av[lane] + w1 * av[lane + 64];
  float s2 = w0 * bv[lane] + w1 * bv[lane + 64];
  #pragma unroll
  for (int off = 32; off > 0; off >>= 1) {
    s1 += __shfl_xor(s1, off);
    s2 += __shfl_xor(s2, off);
  }
  if (lane == 0) { es[r] = s1; ed[r] = s2; }
}

// ---------------- CSR build ----------------
__global__ void count_kernel(const int* __restrict__ dst, int* __restrict__ deg, int E) {
  int e = blockIdx.x * blockDim.x + threadIdx.x;
  if (e >= E) return;
  int d = dst[e];
  if ((unsigned)d < NN) atomicAdd(&deg[d], 1);
}

// -- parallel 3-phase exclusive scan of deg (replaces 118 µs single-block scan) --
__global__ void scan_p1(const int* __restrict__ deg, int* __restrict__ bsum) {
  __shared__ int s[256];
  int t = threadIdx.x;
  int i = blockIdx.x * 256 + t;
  s[t] = (i < NN) ? deg[i] : 0;
  __syncthreads();
  #pragma unroll
  for (int off = 128; off > 0; off >>= 1) {
    if (t < off) s[t] += s[t + off];
    __syncthreads();
  }
  if (t == 0) bsum[blockIdx.x] = s[0];
}
__global__ void scan_p2(const int* __restrict__ bsum, int* __restrict__ boff,
                        int* __restrict__ total_out) {
  __shared__ int s[256];
  int t = threadIdx.x;
  s[t] = (t < SCAN_NB) ? bsum[t] : 0;
  __syncthreads();
  if (t == 0) {
    int r = 0;
    for (int i = 0; i < SCAN_NB; ++i) { int v = s[i]; s[i] = r; r += v; }
    total_out[0] = r;   // rowptr[NN]
  }
  __syncthreads();
  if (t < SCAN_NB) boff[t] = s[t];
}
__global__ void scan_p3(const int* __restrict__ deg, const int* __restrict__ boff,
                        int* __restrict__ rowptr, int* __restrict__ cursor) {
  __shared__ int s[256];
  int t = threadIdx.x;
  int i = blockIdx.x * 256 + t;
  int v = (i < NN) ? deg[i] : 0;
  s[t] = v;
  __syncthreads();
  #pragma unroll
  for (int off = 1; off < 256; off <<= 1) {
    int add = (t >= off) ? s[t - off] : 0;
    __syncthreads();
    s[t] += add;
    __syncthreads();
  }
  if (i < NN) {
    int pos = boff[blockIdx.x] + s[t] - v;   // exclusive
    rowptr[i] = pos;
    cursor[i] = pos;
  }
}

// csr entry = {edge id, src node}
__global__ void scatter_kernel(const int* __restrict__ src, const int* __restrict__ dst,
                               int* __restrict__ cursor, int2* __restrict__ csr2, int E) {
  int e = blockIdx.x * blockDim.x + threadIdx.x;
  if (e >= E) return;
  int d = dst[e];
  if ((unsigned)d >= NN) return;
  int s = src[e]; if ((unsigned)s >= NN) s = 0;
  int p = atomicAdd(&cursor[d], 1);
  if ((unsigned)p < (unsigned)E) csr2[p] = make_int2(e, s);
}

// ---- layer-1 edge logits (4 heads) + atomic max per dst ----
__global__ void elog1(const int* __restrict__ src, const int* __restrict__ dst,
                      const float4* __restrict__ es1, const float4* __restrict__ ed1,
                      float4* __restrict__ evalw, unsigned* __restrict__ m1) {
  int e = blockIdx.x * 256 + threadIdx.x;
  if (e >= EE) return;
  int s = src[e]; if ((unsigned)s >= NN) s = 0;
  int d = dst[e]; if ((unsigned)d >= NN) d = 0;
  float4 a = es1[s], b = ed1[d];
  float v[4] = {a.x + b.x, a.y + b.y, a.z + b.z, a.w + b.w};
  #pragma unroll
  for (int h = 0; h < 4; ++h) v[h] = v[h] >= 0.f ? v[h] : 0.2f * v[h];
  evalw[e] = make_float4(v[0], v[1], v[2], v[3]);
  #pragma unroll
  for (int h = 0; h < 4; ++h)
    atomicMax(m1 + d * 4 + h, __float_as_uint(fmaxf(v[h], 0.f)));
}

// ---- layer-1 edge weights: w = exp(v - m[dst]) in-place + atomic sum ----
__global__ void ewei1(const int* __restrict__ dst, float4* __restrict__ evalw,
                      const unsigned* __restrict__ m1, float* __restrict__ sum1) {
  int e = blockIdx.x * 256 + threadIdx.x;
  if (e >= EE) return;
  int d = dst[e]; if ((unsigned)d >= NN) d = 0;
  float4 v = evalw[e];
  const unsigned* mp = m1 + d * 4;
  float w0 = expf(v.x - __uint_as_float(mp[0]));
  float w1 = expf(v.y - __uint_as_float(mp[1]));
  float w2 = expf(v.z - __uint_as_float(mp[2]));
  float w3 = expf(v.w - __uint_as_float(mp[3]));
  evalw[e] = make_float4(w0, w1, w2, w3);
  atomicAdd(sum1 + d * 4 + 0, w0);
  atomicAdd(sum1 + d * 4 + 1, w1);
  atomicAdd(sum1 + d * 4 + 2, w2);
  atomicAdd(sum1 + d * 4 + 3, w3);
}

// ---- layer-1 aggregate, all heads: wave per node, 8 feats/lane ----
__global__ __launch_bounds__(256)
void agg1_all(const int2* __restrict__ csr2, const int* __restrict__ rowptr,
              const float4* __restrict__ w4arr, const float* __restrict__ sum1,
              const bf16* __restrict__ Wh1, bf16* __restrict__ h1) {
  int wid = threadIdx.x >> 6, lane = threadIdx.x & 63;
  int node = blockIdx.x * 4 + wid;
  if (node >= NN) return;
  int b = rowptr[node], e = rowptr[node + 1];
  if (b < 0) b = 0; if (e > EE) e = EE;
  int h = lane >> 4;
  float acc[8] = {};
  for (int j = b; j < e; ++j) {
    int2 c = csr2[j];
    float4 w4 = w4arr[c.x];
    float wv = h == 0 ? w4.x : h == 1 ? w4.y : h == 2 ? w4.z : w4.w;
    bf16x8 r = *(const bf16x8*)(Wh1 + (size_t)c.y * C1 + lane * 8);
    #pragma unroll
    for (int k = 0; k < 8; ++k) acc[k] += wv * (float)r[k];
  }
  float scale = 1.f / (sum1[node * 4 + h] + 1e-8f);
  bf16x8 o;
  #pragma unroll
  for (int k = 0; k < 8; ++k) o[k] = (__bf16)(acc[k] * scale);
  *(bf16x8*)(h1 + (size_t)node * C1 + lane * 8) = o;
}

// ---- layer-2 edge logits/weights (H=1) ----
__global__ void elog2(const int* __restrict__ src, const int* __restrict__ dst,
                      const float* __restrict__ es2, const float* __restrict__ ed2,
                      float* __restrict__ w2e, unsigned* __restrict__ m2) {
  int e = blockIdx.x * 256 + threadIdx.x;
  if (e >= EE) return;
  int s = src[e]; if ((unsigned)s >= NN) s = 0;
  int d = dst[e]; if ((unsigned)d >= NN) d = 0;
  float v = es2[s] + ed2[d];
  v = v >= 0.f ? v : 0.2f * v;
  w2e[e] = v;
  atomicMax(m2 + d, __float_as_uint(fmaxf(v, 0.f)));
}
__global__ void ewei2(const int* __restrict__ dst, float* __restrict__ w2e,
                      const unsigned* __restrict__ m2, float* __restrict__ sum2) {
  int e = blockIdx.x * 256 + threadIdx.x;
  if (e >= EE) return;
  int d = dst[e]; if ((unsigned)d >= NN) d = 0;
  float w = expf(w2e[e] - __uint_as_float(m2[d]));
  w2e[e] = w;
  atomicAdd(sum2 + d, w);
}

// ---- layer-2 aggregate: wave per node, 2 feats/lane ----
__global__ __launch_bounds__(256)
void agg2_all(const int2* __restrict__ csr2, const int* __restrict__ rowptr,
              const float* __restrict__ w2e, const float* __restrict__ sum2,
              const bf16* __restrict__ Wh2, bf16* __restrict__ h2p,
              float* __restrict__ invs2) {
  int wid = threadIdx.x >> 6, lane = threadIdx.x & 63;
  int node = blockIdx.x * 4 + wid;
  if (node >= NN) return;
  int b = rowptr[node], e = rowptr[node + 1];
  if (b < 0) b = 0; if (e > EE) e = EE;
  float a0 = 0.f, a1 = 0.f;
  for (int j = b; j < e; ++j) {
    int2 c = csr2[j];
    float w = w2e[c.x];
    bf16x2v r = *(const bf16x2v*)(Wh2 + (size_t)c.y * HID + lane * 2);
    a0 += w * (float)r[0];
    a1 += w * (float)r[1];
  }
  float scale = 1.f / (sum2[node] + 1e-8f);
  bf16x2v o;
  o[0] = (__bf16)(a0 * scale);
  o[1] = (__bf16)(a1 * scale);
  *(bf16x2v*)(h2p + (size_t)node * HID + lane * 2) = o;
  if (lane == 0) invs2[node] = scale;
}

// ---- attention output (edge-parallel) ----
__global__ void attn_edge(const int* __restrict__ dst, const float* __restrict__ w2e,
                          const float* __restrict__ invs2, float* __restrict__ attn_out) {
  int e = blockIdx.x * 256 + threadIdx.x;
  if (e >= EE) return;
  int d = dst[e]; if ((unsigned)d >= NN) d = 0;
  attn_out[e] = w2e[e] * invs2[d];
}

// ---- ELU in place (bf16) + per-column fp32 sum/sumsq; blockDim == C ----
__global__ void elu_stats(bf16* __restrict__ X, float* __restrict__ cs, float* __restrict__ cq,
                          int Nrows, int C) {
  int c = threadIdx.x;
  int rpb = (Nrows + gridDim.x - 1) / gridDim.x;
  int r0 = blockIdx.x * rpb, r1 = min(r0 + rpb, Nrows);
  float s = 0.f, s2 = 0.f;
  for (int r = r0; r < r1; ++r) {
    size_t idx = (size_t)r * C + c;
    float v = b2f(X[idx]);
    v = v > 0.f ? v : expm1f(v);
    X[idx] = f2b(v);
    s += v; s2 += v * v;
  }
  atomicAdd(&cs[c], s);
  atomicAdd(&cq[c], s2);
}

__global__ void bn_apply(const bf16* __restrict__ in, bf16* __restrict__ out,
                         float* __restrict__ out2,
                         const float* __restrict__ cs, const float* __restrict__ cq,
                         const float* __restrict__ gamma, const float* __restrict__ beta,
                         int C, size_t total, float invN) {
  size_t i = (size_t)blockIdx.x * blockDim.x + threadIdx.x;
  if (i >= total) return;
  int c = (int)(i % C);
  float mu = cs[c] * invN;
  float var = cq[c] * invN - mu * mu;
  float v = (b2f(in[i]) - mu) * rsqrtf(fmaxf(var, 0.f) + 1e-5f) * gamma[c] + beta[c];
  out[i] = f2b(v);
  if (out2) out2[i] = v;
}

// ---- global mean pool ----
__global__ void pool_kernel(const bf16* __restrict__ h2, const int* __restrict__ batch,
                            float* __restrict__ pooled, float* __restrict__ cnt) {
  __shared__ float acc[NGR * HID];
  __shared__ float ccnt[NGR];
  int f = threadIdx.x;  // 128 threads
  for (int i = f; i < NGR * HID; i += HID) acc[i] = 0.f;
  if (f < NGR) ccnt[f] = 0.f;
  __syncthreads();
  for (int r = blockIdx.x; r < NN; r += gridDim.x) {
    int g = batch[r]; if ((unsigned)g >= NGR) g = 0;
    acc[g * HID + f] += b2f(h2[(size_t)r * HID + f]);
    if (f == 0) ccnt[g] += 1.f;
  }
  __syncthreads();
  for (int i = f; i < NGR * HID; i += HID) atomicAdd(&pooled[i], acc[i]);
  if (f < NGR) atomicAdd(&cnt[f], ccnt[f]);
}

// ---- classifier (tiny, single block) ----
__global__ void cls_kernel(const float* __restrict__ pooled, const float* __restrict__ cnt,
                           const float* __restrict__ w1, const float* __restrict__ b1,
                           const float* __restrict__ w2, const float* __restrict__ b2,
                           float* __restrict__ out) {
  __shared__ float repr[NGR * HID];
  __shared__ float hid[NGR * 64];
  int t = threadIdx.x;  // 128
  for (int i = t; i < NGR * HID; i += 128) {
    int g = i >> 7;
    repr[i] = pooled[i] / fmaxf(cnt[g], 1.f);
  }
  __syncthreads();
  for (int i = t; i < NGR * 64; i += 128) {
    int g = i >> 6, j = i & 63;
    float s = b1[j];
    for (int c = 0; c < HID; ++c) s += repr[g * HID + c] * w1[c * 64 + j];
    hid[i] = fmaxf(s, 0.f);
  }
  __syncthreads();
  if (t < NGR * 2) {
    int g = t >> 1, k = t & 1;
    float s = b2[k];
    for (int j = 0; j < 64; ++j) s += hid[g * 64 + j] * w2[j * 2 + k];
    out[t] = s;
  }
}

// ---- edge importance from fused PQ (N,256) ----
__global__ void eimp_kernel(const int* __restrict__ src, const int* __restrict__ dstp,
                            const bf16* __restrict__ PQ,
                            const float* __restrict__ b1, const float* __restrict__ w2,
                            const float* __restrict__ b2, float* __restrict__ out) {
  int wid = threadIdx.x >> 6, lane = threadIdx.x & 63;
  int e = blockIdx.x * 4 + wid;
  if (e >= EE) return;
  int s = src[e]; if ((unsigned)s >= NN) s = 0;
  int d = dstp[e]; if ((unsigned)d >= NN) d = 0;
  bf16x2v p2 = *(const bf16x2v*)(PQ + (size_t)s * 256 + lane * 2);
  bf16x2v q2 = *(const bf16x2v*)(PQ + (size_t)d * 256 + 128 + lane * 2);
  float acc = 0.f;
  #pragma unroll
  for (int r = 0; r < 2; ++r) {
    int j = lane * 2 + r;
    float hh = (float)p2[r] + (float)q2[r] + b1[j];
    hh = fmaxf(hh, 0.f);
    acc += hh * w2[j];
  }
  #pragma unroll
  for (int off = 32; off > 0; off >>= 1) acc += __shfl_xor(acc, off);
  if (lane == 0) {
    float z = acc + b2[0];
    out[e] = 1.f / (1.f + expf(-z));
  }
}

extern "C" void kernel_launch(void* const* d_in, const int* in_sizes, int n_in,
                              void* d_out, int out_size, void* d_ws, size_t ws_size,
                              hipStream_t stream) {
  const float* x      = (const float*)d_in[0];
  const int*   ei     = (const int*)d_in[1];
  const int*   batch  = (const int*)d_in[2];
  const float* W1     = (const float*)d_in[3];
  const float* a_src1 = (const float*)d_in[4];
  const float* a_dst1 = (const float*)d_in[5];
  const float* W2     = (const float*)d_in[6];
  const float* a_src2 = (const float*)d_in[7];
  const float* a_dst2 = (const float*)d_in[8];
  const float* bn1_g  = (const float*)d_in[9];
  const float* bn1_b  = (const float*)d_in[10];
  const float* bn2_g  = (const float*)d_in[11];
  const float* bn2_b  = (const float*)d_in[12];
  const float* cls_w1 = (const float*)d_in[13];
  const float* cls_b1 = (const float*)d_in[14];
  const float* cls_w2 = (const float*)d_in[15];
  const float* cls_b2 = (const float*)d_in[16];
  const float* ep_w1  = (const float*)d_in[17];
  const float* ep_b1  = (const float*)d_in[18];
  const float* ep_w2  = (const float*)d_in[19];
  const float* ep_b2  = (const float*)d_in[20];

  const int* srcp = ei;
  const int* dstp = ei + EE;

  // ---- workspace layout (bytes), peak ~118.9 MB, hazard-checked ----
  char* base = (char*)d_ws;
  // region A [0, 51.2e6): xb first (28.8e6), then h1 (51.2e6) — xb dead before agg1 writes h1
  bf16* xb  = (bf16*)(base);
  bf16* h1  = (bf16*)(base);
  // region B [51.2e6, 102.4e6): Wh1; later Wh2/h2p/h2; later PQ over dead Wh2+h2p
  bf16* Wh1 = (bf16*)(base + 51200000);
  bf16* Wh2 = (bf16*)(base + 51200000);   // (N,128) after agg1 (Wh1 dead)
  bf16* h2p = (bf16*)(base + 64000000);   // (N,128)
  bf16* h2  = (bf16*)(base + 76800000);   // (N,128)
  bf16* PQ  = (bf16*)(base + 51200000);   // (N,256) after bn2 (Wh2,h2p dead)
  // region S [102.4e6, ...): small buffers; first chunk is zeroed in one call
  unsigned* m1  = (unsigned*)(base + 102400000);  // (N,4)
  float* sum1   = (float*)(base + 103200000);     // (N,4)
  unsigned* m2  = (unsigned*)(base + 104000000);  // (N)
  float* sum2   = (float*)(base + 104200000);     // (N)
  int* deg      = (int*)(base + 104400000);       // (N)
  float* stats  = (float*)(base + 104600000);     // 3344 floats
  //   zero range = [102400000, 104613376) = 553,344 words
  float* cs1 = stats,        *cq1 = stats + 512;
  float* cs2 = stats + 1024, *cq2 = stats + 1152;
  float* pooled = stats + 1280;                   // 16*128
  float* cnt    = stats + 3328;                   // 16
  float* es1    = (float*)(base + 104613376);     // (N,4)
  float* ed1    = (float*)(base + 105413376);     // (N,4)
  float* evalw  = (float*)(base + 106213376);     // (E,4) logits -> weights
  float* es2    = (float*)(base + 112613376);     // (N)
  float* ed2    = (float*)(base + 112813376);     // (N)
  float* w2e    = (float*)(base + 113013376);     // (E)
  float* invs2  = (float*)(base + 114613376);     // (N)
  int* rowptr   = (int*)(base + 114813376);       // (N+1)
  int* cursor   = (int*)(base + 115013380);       // (N)
  int2* csr2    = (int2*)(base + 115213384);      // (E) {edge, src}
  bf16* B1t     = (bf16*)(base + 118413392);      // (512,288)
  bf16* B2t     = (bf16*)(base + 118708304);      // (128,512)
  bf16* BPt     = (bf16*)(base + 118839376);      // (256,128) -> ends 118,904,912
  // scan scratch: aliases evalw (not live until elog1, which runs after scatter)
  int* bsum = (int*)evalw;          // SCAN_NB ints
  int* boff = bsum + 256;           // SCAN_NB ints

  float* out        = (float*)d_out;
  float* out_logits = out;                          // 32
  float* out_h2     = out + 32;                     // N*128
  float* out_imp    = out + 32 + (size_t)NN * HID;  // E
  float* out_attn   = out_imp + EE;                 // E

  // zero m1/sum1/m2/sum2/deg/stats in one call (ws poisoned 0xAA each call)
  zero_words<<<(553344 + 255) / 256, 256, 0, stream>>>((unsigned int*)m1, 553344);

  // prep: bf16 conversions / transposes
  conv_x<<<(NN * KP1 + 255) / 256, 256, 0, stream>>>(x, xb);
  prep_b1t<<<(C1 * KP1 + 255) / 256, 256, 0, stream>>>(W1, B1t);
  prep_b2t<<<(HID * C1 + 255) / 256, 256, 0, stream>>>(W2, B2t);
  prep_bpt<<<(256 * HID + 255) / 256, 256, 0, stream>>>(ep_w1, BPt);

  // CSR by destination (entries carry {edge, src}); parallel 3-phase scan
  count_kernel<<<(EE + 255) / 256, 256, 0, stream>>>(dstp, deg, EE);
  scan_p1<<<SCAN_NB, 256, 0, stream>>>(deg, bsum);
  scan_p2<<<1, 256, 0, stream>>>(bsum, boff, rowptr + NN);
  scan_p3<<<SCAN_NB, 256, 0, stream>>>(deg, boff, rowptr, cursor);
  scatter_kernel<<<(EE + 255) / 256, 256, 0, stream>>>(srcp, dstp, cursor, csr2, EE);

  // ---- layer 1: one GEMM (all heads), edge-parallel softmax, one aggregate ----
  dim3 g1(C1 / 128, (NN + 127) / 128);
  gemm_mfma<<<g1, 256, 0, stream>>>(xb, B1t, Wh1, NN, KP1, C1);
  edot_all<<<(NN + 3) / 4, 256, 0, stream>>>(Wh1, a_src1, a_dst1, es1, ed1);
  elog1<<<(EE + 255) / 256, 256, 0, stream>>>(srcp, dstp, (const float4*)es1,
                                              (const float4*)ed1, (float4*)evalw, m1);
  ewei1<<<(EE + 255) / 256, 256, 0, stream>>>(dstp, (float4*)evalw, m1, sum1);
  agg1_all<<<(NN + 3) / 4, 256, 0, stream>>>(csr2, rowptr, (const float4*)evalw, sum1,
                                             Wh1, h1);

  elu_stats<<<400, C1, 0, stream>>>(h1, cs1, cq1, NN, C1);
  {
    size_t total = (size_t)NN * C1;
    bn_apply<<<(unsigned)((total + 255) / 256), 256, 0, stream>>>(
        h1, h1, (float*)nullptr, cs1, cq1, bn1_g, bn1_b, C1, total, 1.f / NN);
  }

  // ---- layer 2 ----
  dim3 g2(1, (NN + 127) / 128);
  gemm_mfma<<<g2, 256, 0, stream>>>(h1, B2t, Wh2, NN, C1, HID);
  edot1<<<(NN + 3) / 4, 256, 0, stream>>>(Wh2, a_src2, a_dst2, es2, ed2);
  elog2<<<(EE + 255) / 256, 256, 0, stream>>>(srcp, dstp, es2, ed2, w2e, m2);
  ewei2<<<(EE + 255) / 256, 256, 0, stream>>>(dstp, w2e, m2, sum2);
  agg2_all<<<(NN + 3) / 4, 256, 0, stream>>>(csr2, rowptr, w2e, sum2, Wh2, h2p, invs2);
  attn_edge<<<(EE + 255) / 256, 256, 0, stream>>>(dstp, w2e, invs2, out_attn);

  elu_stats<<<400, HID, 0, stream>>>(h2p, cs2, cq2, NN, HID);
  {
    size_t total = (size_t)NN * HID;
    bn_apply<<<(unsigned)((total + 255) / 256), 256, 0, stream>>>(
        h2p, h2, out_h2, cs2, cq2, bn2_g, bn2_b, HID, total, 1.f / NN);
  }

  // ---- heads ----
  pool_kernel<<<256, HID, 0, stream>>>(h2, batch, pooled, cnt);
  cls_kernel<<<1, 128, 0, stream>>>(pooled, cnt, cls_w1, cls_b1, cls_w2, cls_b2, out_logits);

  dim3 gpq(2, (NN + 127) / 128);
  gemm_mfma<<<gpq, 256, 0, stream>>>(h2, BPt, PQ, NN, HID, 256);
  eimp_kernel<<<(EE + 3) / 4, 256, 0, stream>>>(srcp, dstp, PQ, ep_b1, ep_w2, ep_b2, out_imp);
}

// Round 7
// 940.687 us; speedup vs baseline: 2.2918x; 1.1007x over previous
//
#include <hip/hip_runtime.h>
#include <hip/hip_bf16.h>
#include <math.h>

typedef __hip_bfloat16 bf16;
typedef __bf16 bf16x8 __attribute__((ext_vector_type(8)));
typedef __bf16 bf16x2v __attribute__((ext_vector_type(2)));
typedef float f32x4 __attribute__((ext_vector_type(4)));

#define NN 50000
#define EE 400000
#define FIN 262
#define KP1 288   /* FIN padded to multiple of 32 */
#define HID 128
#define NH 4
#define C1 512   /* HID*NH */
#define NGR 16
#define SCAN_NB ((NN + 255) / 256)   /* 196 */

__device__ __forceinline__ float b2f(bf16 x){ return __bfloat162float(x); }
__device__ __forceinline__ bf16 f2b(float x){ return __float2bfloat16(x); }

__global__ void zero_words(unsigned int* __restrict__ p, int n) {
  int i = blockIdx.x * 256 + threadIdx.x;
  if (i < n) p[i] = 0u;
}

// ================= MFMA GEMM: C(M,N) = A(M,K) @ B(K,N) =================
// A: (M,K) bf16 row-major; Bt: (N,K) bf16 row-major (pre-transposed B).
// K % 32 == 0, Ncols % 128 == 0. C: (M,N) bf16.
__global__ __launch_bounds__(256)
void gemm_mfma(const bf16* __restrict__ A, const bf16* __restrict__ Bt,
               bf16* __restrict__ C, int M, int K, int Ncols) {
  __shared__ __align__(16) __bf16 As[128 * 40];  // +8 pad: 2-way banks only (free)
  __shared__ __align__(16) __bf16 Bs[128 * 40];
  int bm = blockIdx.y * 128, bn = blockIdx.x * 128;
  int tid = threadIdx.x;
  int wave = tid >> 6, lane = tid & 63;
  int quad = lane >> 4, l16 = lane & 15;
  int wm = (wave >> 1) * 64, wn = (wave & 1) * 64;
  f32x4 acc[4][4];
  #pragma unroll
  for (int i = 0; i < 4; ++i)
    #pragma unroll
    for (int j = 0; j < 4; ++j)
      acc[i][j] = (f32x4){0.f, 0.f, 0.f, 0.f};

  for (int k0 = 0; k0 < K; k0 += 32) {
    #pragma unroll
    for (int l = 0; l < 2; ++l) {
      int e = l * 2048 + tid * 8;
      int row = e >> 5, col = e & 31;           // 128 rows x 32 cols
      uint4 va = {0u, 0u, 0u, 0u};
      int gm = bm + row;
      if (gm < M) va = *(const uint4*)(A + (size_t)gm * K + k0 + col);
      *(uint4*)(&As[row * 40 + col]) = va;
      uint4 vb = {0u, 0u, 0u, 0u};
      int gn = bn + row;
      if (gn < Ncols) vb = *(const uint4*)(Bt + (size_t)gn * K + k0 + col);
      *(uint4*)(&Bs[row * 40 + col]) = vb;
    }
    __syncthreads();
    bf16x8 af[4], bf_[4];
    #pragma unroll
    for (int i = 0; i < 4; ++i)
      af[i] = *(const bf16x8*)(&As[(wm + i * 16 + l16) * 40 + quad * 8]);
    #pragma unroll
    for (int j = 0; j < 4; ++j)
      bf_[j] = *(const bf16x8*)(&Bs[(wn + j * 16 + l16) * 40 + quad * 8]);
    #pragma unroll
    for (int i = 0; i < 4; ++i)
      #pragma unroll
      for (int j = 0; j < 4; ++j)
        acc[i][j] = __builtin_amdgcn_mfma_f32_16x16x32_bf16(af[i], bf_[j], acc[i][j], 0, 0, 0);
    __syncthreads();
  }
  #pragma unroll
  for (int i = 0; i < 4; ++i) {
    #pragma unroll
    for (int r = 0; r < 4; ++r) {
      int gm = bm + wm + i * 16 + quad * 4 + r;
      if (gm >= M) continue;
      #pragma unroll
      for (int j = 0; j < 4; ++j) {
        int gn = bn + wn + j * 16 + l16;
        C[(size_t)gm * Ncols + gn] = f2b(acc[i][j][r]);
      }
    }
  }
}

// ---- prep kernels ----
__global__ void conv_x(const float* __restrict__ x, bf16* __restrict__ xb) {
  int i = blockIdx.x * 256 + threadIdx.x;
  if (i >= NN * KP1) return;
  int row = i / KP1, col = i - row * KP1;
  xb[i] = (col < FIN) ? f2b(x[(size_t)row * FIN + col]) : f2b(0.f);
}
__global__ void prep_b1t(const float* __restrict__ W1, bf16* __restrict__ B1t) {
  int i = blockIdx.x * 256 + threadIdx.x;
  if (i >= C1 * KP1) return;
  int n = i / KP1, k = i - n * KP1;   // n = h*128 + o
  int h = n >> 7, o = n & 127;
  B1t[i] = (k < FIN) ? f2b(W1[((size_t)h * FIN + k) * HID + o]) : f2b(0.f);
}
__global__ void prep_b2t(const float* __restrict__ W2, bf16* __restrict__ B2t) {
  int i = blockIdx.x * 256 + threadIdx.x;
  if (i >= HID * C1) return;
  int n = i >> 9, k = i & 511;
  B2t[i] = f2b(W2[(size_t)k * HID + n]);
}
__global__ void prep_bpt(const float* __restrict__ epw1, bf16* __restrict__ BPt) {
  int i = blockIdx.x * 256 + threadIdx.x;
  if (i >= 256 * HID) return;
  int n = i >> 7, k = i & 127;
  float v = (n < 128) ? epw1[(size_t)k * HID + n] : epw1[(size_t)(128 + k) * HID + (n - 128)];
  BPt[i] = f2b(v);
}

// ---- edot over all 4 heads: wave per node; lane: head = lane>>4, 8 feats ----
__global__ void edot_all(const bf16* __restrict__ Wh1, const float* __restrict__ av,
                         const float* __restrict__ bv, float* __restrict__ es1,
                         float* __restrict__ ed1) {
  int wid = threadIdx.x >> 6, lane = threadIdx.x & 63;
  int n = blockIdx.x * 4 + wid;
  if (n >= NN) return;
  int h = lane >> 4, c16 = lane & 15;
  int fbase = h * HID + c16 * 8;
  bf16x8 r = *(const bf16x8*)(Wh1 + (size_t)n * C1 + fbase);
  float s1 = 0.f, s2 = 0.f;
  #pragma unroll
  for (int j = 0; j < 8; ++j) {
    float rv = (float)r[j];
    s1 += rv * av[fbase + j];
    s2 += rv * bv[fbase + j];
  }
  #pragma unroll
  for (int off = 8; off > 0; off >>= 1) {
    s1 += __shfl_xor(s1, off);
    s2 += __shfl_xor(s2, off);
  }
  if (c16 == 0) { es1[n * 4 + h] = s1; ed1[n * 4 + h] = s2; }
}

// per-node dot (H=1, 128-wide); one wave per node
__global__ void edot1(const bf16* __restrict__ Wh, const float* __restrict__ av,
                      const float* __restrict__ bv, float* __restrict__ es,
                      float* __restrict__ ed) {
  int wid = threadIdx.x >> 6, lane = threadIdx.x & 63;
  int r = blockIdx.x * 4 + wid;
  if (r >= NN) return;
  const bf16* row = Wh + (size_t)r * HID;
  float w0 = b2f(row[lane]), w1 = b2f(row[lane + 64]);
  float s1 = w0 * av[lane] + w1 * av[lane + 64];
  float s2 = w0 * bv[lane] + w1 * bv[lane + 64];
  #pragma unroll
  for (int off = 32; off > 0; off >>= 1) {
    s1 += __shfl_xor(s1, off);
    s2 += __shfl_xor(s2, off);
  }
  if (lane == 0) { es[r] = s1; ed[r] = s2; }
}

// ---------------- CSR build ----------------
__global__ void count_kernel(const int* __restrict__ dst, int* __restrict__ deg, int E) {
  int e = blockIdx.x * blockDim.x + threadIdx.x;
  if (e >= E) return;
  int d = dst[e];
  if ((unsigned)d < NN) atomicAdd(&deg[d], 1);
}

// -- parallel 3-phase exclusive scan of deg --
__global__ void scan_p1(const int* __restrict__ deg, int* __restrict__ bsum) {
  __shared__ int s[256];
  int t = threadIdx.x;
  int i = blockIdx.x * 256 + t;
  s[t] = (i < NN) ? deg[i] : 0;
  __syncthreads();
  #pragma unroll
  for (int off = 128; off > 0; off >>= 1) {
    if (t < off) s[t] += s[t + off];
    __syncthreads();
  }
  if (t == 0) bsum[blockIdx.x] = s[0];
}
__global__ void scan_p2(const int* __restrict__ bsum, int* __restrict__ boff,
                        int* __restrict__ total_out) {
  __shared__ int s[256];
  int t = threadIdx.x;
  s[t] = (t < SCAN_NB) ? bsum[t] : 0;
  __syncthreads();
  if (t == 0) {
    int r = 0;
    for (int i = 0; i < SCAN_NB; ++i) { int v = s[i]; s[i] = r; r += v; }
    total_out[0] = r;   // rowptr[NN]
  }
  __syncthreads();
  if (t < SCAN_NB) boff[t] = s[t];
}
__global__ void scan_p3(const int* __restrict__ deg, const int* __restrict__ boff,
                        int* __restrict__ rowptr, int* __restrict__ cursor) {
  __shared__ int s[256];
  int t = threadIdx.x;
  int i = blockIdx.x * 256 + t;
  int v = (i < NN) ? deg[i] : 0;
  s[t] = v;
  __syncthreads();
  #pragma unroll
  for (int off = 1; off < 256; off <<= 1) {
    int add = (t >= off) ? s[t - off] : 0;
    __syncthreads();
    s[t] += add;
    __syncthreads();
  }
  if (i < NN) {
    int pos = boff[blockIdx.x] + s[t] - v;   // exclusive
    rowptr[i] = pos;
    cursor[i] = pos;
  }
}

// csr entry = {edge id, src node}
__global__ void scatter_kernel(const int* __restrict__ src, const int* __restrict__ dst,
                               int* __restrict__ cursor, int2* __restrict__ csr2, int E) {
  int e = blockIdx.x * blockDim.x + threadIdx.x;
  if (e >= E) return;
  int d = dst[e];
  if ((unsigned)d >= NN) return;
  int s = src[e]; if ((unsigned)s >= NN) s = 0;
  int p = atomicAdd(&cursor[d], 1);
  if ((unsigned)p < (unsigned)E) csr2[p] = make_int2(e, s);
}

// ---- layer-1 edge logits (4 heads) + atomic max per dst ----
__global__ void elog1(const int* __restrict__ src, const int* __restrict__ dst,
                      const float4* __restrict__ es1, const float4* __restrict__ ed1,
                      float4* __restrict__ evalw, unsigned* __restrict__ m1) {
  int e = blockIdx.x * 256 + threadIdx.x;
  if (e >= EE) return;
  int s = src[e]; if ((unsigned)s >= NN) s = 0;
  int d = dst[e]; if ((unsigned)d >= NN) d = 0;
  float4 a = es1[s], b = ed1[d];
  float v[4] = {a.x + b.x, a.y + b.y, a.z + b.z, a.w + b.w};
  #pragma unroll
  for (int h = 0; h < 4; ++h) v[h] = v[h] >= 0.f ? v[h] : 0.2f * v[h];
  evalw[e] = make_float4(v[0], v[1], v[2], v[3]);
  #pragma unroll
  for (int h = 0; h < 4; ++h)
    atomicMax(m1 + d * 4 + h, __float_as_uint(fmaxf(v[h], 0.f)));
}

// ---- layer-1 edge weights: w = exp(v - m[dst]) in-place + atomic sum ----
__global__ void ewei1(const int* __restrict__ dst, float4* __restrict__ evalw,
                      const unsigned* __restrict__ m1, float* __restrict__ sum1) {
  int e = blockIdx.x * 256 + threadIdx.x;
  if (e >= EE) return;
  int d = dst[e]; if ((unsigned)d >= NN) d = 0;
  float4 v = evalw[e];
  const unsigned* mp = m1 + d * 4;
  float w0 = expf(v.x - __uint_as_float(mp[0]));
  float w1 = expf(v.y - __uint_as_float(mp[1]));
  float w2 = expf(v.z - __uint_as_float(mp[2]));
  float w3 = expf(v.w - __uint_as_float(mp[3]));
  evalw[e] = make_float4(w0, w1, w2, w3);
  atomicAdd(sum1 + d * 4 + 0, w0);
  atomicAdd(sum1 + d * 4 + 1, w1);
  atomicAdd(sum1 + d * 4 + 2, w2);
  atomicAdd(sum1 + d * 4 + 3, w3);
}

// ---- layer-1 aggregate, all heads: wave per node, 8 feats/lane ----
__global__ __launch_bounds__(256)
void agg1_all(const int2* __restrict__ csr2, const int* __restrict__ rowptr,
              const float4* __restrict__ w4arr, const float* __restrict__ sum1,
              const bf16* __restrict__ Wh1, bf16* __restrict__ h1) {
  int wid = threadIdx.x >> 6, lane = threadIdx.x & 63;
  int node = blockIdx.x * 4 + wid;
  if (node >= NN) return;
  int b = rowptr[node], e = rowptr[node + 1];
  if (b < 0) b = 0; if (e > EE) e = EE;
  int h = lane >> 4;
  float acc[8] = {};
  for (int j = b; j < e; ++j) {
    int2 c = csr2[j];
    float4 w4 = w4arr[c.x];
    float wv = h == 0 ? w4.x : h == 1 ? w4.y : h == 2 ? w4.z : w4.w;
    bf16x8 r = *(const bf16x8*)(Wh1 + (size_t)c.y * C1 + lane * 8);
    #pragma unroll
    for (int k = 0; k < 8; ++k) acc[k] += wv * (float)r[k];
  }
  float scale = 1.f / (sum1[node * 4 + h] + 1e-8f);
  bf16x8 o;
  #pragma unroll
  for (int k = 0; k < 8; ++k) o[k] = (__bf16)(acc[k] * scale);
  *(bf16x8*)(h1 + (size_t)node * C1 + lane * 8) = o;
}

// ---- layer-2 edge logits/weights (H=1) ----
__global__ void elog2(const int* __restrict__ src, const int* __restrict__ dst,
                      const float* __restrict__ es2, const float* __restrict__ ed2,
                      float* __restrict__ w2e, unsigned* __restrict__ m2) {
  int e = blockIdx.x * 256 + threadIdx.x;
  if (e >= EE) return;
  int s = src[e]; if ((unsigned)s >= NN) s = 0;
  int d = dst[e]; if ((unsigned)d >= NN) d = 0;
  float v = es2[s] + ed2[d];
  v = v >= 0.f ? v : 0.2f * v;
  w2e[e] = v;
  atomicMax(m2 + d, __float_as_uint(fmaxf(v, 0.f)));
}
__global__ void ewei2(const int* __restrict__ dst, float* __restrict__ w2e,
                      const unsigned* __restrict__ m2, float* __restrict__ sum2) {
  int e = blockIdx.x * 256 + threadIdx.x;
  if (e >= EE) return;
  int d = dst[e]; if ((unsigned)d >= NN) d = 0;
  float w = expf(w2e[e] - __uint_as_float(m2[d]));
  w2e[e] = w;
  atomicAdd(sum2 + d, w);
}

// ---- layer-2 aggregate: wave per node, 2 feats/lane ----
__global__ __launch_bounds__(256)
void agg2_all(const int2* __restrict__ csr2, const int* __restrict__ rowptr,
              const float* __restrict__ w2e, const float* __restrict__ sum2,
              const bf16* __restrict__ Wh2, bf16* __restrict__ h2p,
              float* __restrict__ invs2) {
  int wid = threadIdx.x >> 6, lane = threadIdx.x & 63;
  int node = blockIdx.x * 4 + wid;
  if (node >= NN) return;
  int b = rowptr[node], e = rowptr[node + 1];
  if (b < 0) b = 0; if (e > EE) e = EE;
  float a0 = 0.f, a1 = 0.f;
  for (int j = b; j < e; ++j) {
    int2 c = csr2[j];
    float w = w2e[c.x];
    bf16x2v r = *(const bf16x2v*)(Wh2 + (size_t)c.y * HID + lane * 2);
    a0 += w * (float)r[0];
    a1 += w * (float)r[1];
  }
  float scale = 1.f / (sum2[node] + 1e-8f);
  bf16x2v o;
  o[0] = (__bf16)(a0 * scale);
  o[1] = (__bf16)(a1 * scale);
  *(bf16x2v*)(h2p + (size_t)node * HID + lane * 2) = o;
  if (lane == 0) invs2[node] = scale;
}

// ---- attention output (edge-parallel) ----
__global__ void attn_edge(const int* __restrict__ dst, const float* __restrict__ w2e,
                          const float* __restrict__ invs2, float* __restrict__ attn_out) {
  int e = blockIdx.x * 256 + threadIdx.x;
  if (e >= EE) return;
  int d = dst[e]; if ((unsigned)d >= NN) d = 0;
  attn_out[e] = w2e[e] * invs2[d];
}

// ---- ELU in place (bf16) + per-column fp32 sum/sumsq; blockDim == C ----
__global__ void elu_stats(bf16* __restrict__ X, float* __restrict__ cs, float* __restrict__ cq,
                          int Nrows, int C) {
  int c = threadIdx.x;
  int rpb = (Nrows + gridDim.x - 1) / gridDim.x;
  int r0 = blockIdx.x * rpb, r1 = min(r0 + rpb, Nrows);
  float s = 0.f, s2 = 0.f;
  for (int r = r0; r < r1; ++r) {
    size_t idx = (size_t)r * C + c;
    float v = b2f(X[idx]);
    v = v > 0.f ? v : expm1f(v);
    X[idx] = f2b(v);
    s += v; s2 += v * v;
  }
  atomicAdd(&cs[c], s);
  atomicAdd(&cq[c], s2);
}

__global__ void bn_apply(const bf16* __restrict__ in, bf16* __restrict__ out,
                         float* __restrict__ out2,
                         const float* __restrict__ cs, const float* __restrict__ cq,
                         const float* __restrict__ gamma, const float* __restrict__ beta,
                         int C, size_t total, float invN) {
  size_t i = (size_t)blockIdx.x * blockDim.x + threadIdx.x;
  if (i >= total) return;
  int c = (int)(i % C);
  float mu = cs[c] * invN;
  float var = cq[c] * invN - mu * mu;
  float v = (b2f(in[i]) - mu) * rsqrtf(fmaxf(var, 0.f) + 1e-5f) * gamma[c] + beta[c];
  out[i] = f2b(v);
  if (out2) out2[i] = v;
}

// ---- global mean pool: 32 rows/block, register-accumulate per graph run ----
// batch is sorted, so each thread crosses at most ~1 graph boundary.
__global__ __launch_bounds__(256)
void pool_kernel(const bf16* __restrict__ h2, const int* __restrict__ batch,
                 float* __restrict__ pooled) {
  int t = threadIdx.x;
  int f = t & 127, half = t >> 7;
  int r0 = blockIdx.x * 32;
  int g_cur = -1;
  float acc = 0.f;
  #pragma unroll
  for (int i = 0; i < 16; ++i) {
    int r = r0 + half + 2 * i;
    if (r >= NN) break;
    int g = batch[r]; if ((unsigned)g >= NGR) g = 0;
    float v = b2f(h2[(size_t)r * HID + f]);
    if (g != g_cur) {
      if (g_cur >= 0) atomicAdd(&pooled[g_cur * HID + f], acc);
      g_cur = g; acc = 0.f;
    }
    acc += v;
  }
  if (g_cur >= 0) atomicAdd(&pooled[g_cur * HID + f], acc);
}

// ---- per-graph counts via binary search on sorted batch ----
__global__ void cnt_kernel(const int* __restrict__ batch, float* __restrict__ cnt) {
  int g = threadIdx.x;
  if (g >= NGR) return;
  int a = 0, b = NN;
  while (a < b) { int m = (a + b) >> 1; if (batch[m] < g) a = m + 1; else b = m; }
  int lb = a;
  a = 0; b = NN;
  while (a < b) { int m = (a + b) >> 1; if (batch[m] <= g) a = m + 1; else b = m; }
  cnt[g] = (float)(a - lb);
}

// ---- classifier (tiny, single block) ----
__global__ void cls_kernel(const float* __restrict__ pooled, const float* __restrict__ cnt,
                           const float* __restrict__ w1, const float* __restrict__ b1,
                           const float* __restrict__ w2, const float* __restrict__ b2,
                           float* __restrict__ out) {
  __shared__ float repr[NGR * HID];
  __shared__ float hid[NGR * 64];
  int t = threadIdx.x;  // 128
  for (int i = t; i < NGR * HID; i += 128) {
    int g = i >> 7;
    repr[i] = pooled[i] / fmaxf(cnt[g], 1.f);
  }
  __syncthreads();
  for (int i = t; i < NGR * 64; i += 128) {
    int g = i >> 6, j = i & 63;
    float s = b1[j];
    for (int c = 0; c < HID; ++c) s += repr[g * HID + c] * w1[c * 64 + j];
    hid[i] = fmaxf(s, 0.f);
  }
  __syncthreads();
  if (t < NGR * 2) {
    int g = t >> 1, k = t & 1;
    float s = b2[k];
    for (int j = 0; j < 64; ++j) s += hid[g * 64 + j] * w2[j * 2 + k];
    out[t] = s;
  }
}

// ---- edge importance from fused PQ (N,256) ----
__global__ void eimp_kernel(const int* __restrict__ src, const int* __restrict__ dstp,
                            const bf16* __restrict__ PQ,
                            const float* __restrict__ b1, const float* __restrict__ w2,
                            const float* __restrict__ b2, float* __restrict__ out) {
  int wid = threadIdx.x >> 6, lane = threadIdx.x & 63;
  int e = blockIdx.x * 4 + wid;
  if (e >= EE) return;
  int s = src[e]; if ((unsigned)s >= NN) s = 0;
  int d = dstp[e]; if ((unsigned)d >= NN) d = 0;
  bf16x2v p2 = *(const bf16x2v*)(PQ + (size_t)s * 256 + lane * 2);
  bf16x2v q2 = *(const bf16x2v*)(PQ + (size_t)d * 256 + 128 + lane * 2);
  float acc = 0.f;
  #pragma unroll
  for (int r = 0; r < 2; ++r) {
    int j = lane * 2 + r;
    float hh = (float)p2[r] + (float)q2[r] + b1[j];
    hh = fmaxf(hh, 0.f);
    acc += hh * w2[j];
  }
  #pragma unroll
  for (int off = 32; off > 0; off >>= 1) acc += __shfl_xor(acc, off);
  if (lane == 0) {
    float z = acc + b2[0];
    out[e] = 1.f / (1.f + expf(-z));
  }
}

extern "C" void kernel_launch(void* const* d_in, const int* in_sizes, int n_in,
                              void* d_out, int out_size, void* d_ws, size_t ws_size,
                              hipStream_t stream) {
  const float* x      = (const float*)d_in[0];
  const int*   ei     = (const int*)d_in[1];
  const int*   batch  = (const int*)d_in[2];
  const float* W1     = (const float*)d_in[3];
  const float* a_src1 = (const float*)d_in[4];
  const float* a_dst1 = (const float*)d_in[5];
  const float* W2     = (const float*)d_in[6];
  const float* a_src2 = (const float*)d_in[7];
  const float* a_dst2 = (const float*)d_in[8];
  const float* bn1_g  = (const float*)d_in[9];
  const float* bn1_b  = (const float*)d_in[10];
  const float* bn2_g  = (const float*)d_in[11];
  const float* bn2_b  = (const float*)d_in[12];
  const float* cls_w1 = (const float*)d_in[13];
  const float* cls_b1 = (const float*)d_in[14];
  const float* cls_w2 = (const float*)d_in[15];
  const float* cls_b2 = (const float*)d_in[16];
  const float* ep_w1  = (const float*)d_in[17];
  const float* ep_b1  = (const float*)d_in[18];
  const float* ep_w2  = (const float*)d_in[19];
  const float* ep_b2  = (const float*)d_in[20];

  const int* srcp = ei;
  const int* dstp = ei + EE;

  // ---- workspace layout (bytes), peak ~118.9 MB, hazard-checked ----
  char* base = (char*)d_ws;
  bf16* xb  = (bf16*)(base);
  bf16* h1  = (bf16*)(base);
  bf16* Wh1 = (bf16*)(base + 51200000);
  bf16* Wh2 = (bf16*)(base + 51200000);   // (N,128) after agg1 (Wh1 dead)
  bf16* h2p = (bf16*)(base + 64000000);   // (N,128)
  bf16* h2  = (bf16*)(base + 76800000);   // (N,128)
  bf16* PQ  = (bf16*)(base + 51200000);   // (N,256) after bn2 (Wh2,h2p dead)
  unsigned* m1  = (unsigned*)(base + 102400000);  // (N,4)
  float* sum1   = (float*)(base + 103200000);     // (N,4)
  unsigned* m2  = (unsigned*)(base + 104000000);  // (N)
  float* sum2   = (float*)(base + 104200000);     // (N)
  int* deg      = (int*)(base + 104400000);       // (N)
  float* stats  = (float*)(base + 104600000);     // 3344 floats
  float* cs1 = stats,        *cq1 = stats + 512;
  float* cs2 = stats + 1024, *cq2 = stats + 1152;
  float* pooled = stats + 1280;                   // 16*128
  float* cnt    = stats + 3328;                   // 16
  float* es1    = (float*)(base + 104613376);     // (N,4)
  float* ed1    = (float*)(base + 105413376);     // (N,4)
  float* evalw  = (float*)(base + 106213376);     // (E,4) logits -> weights
  float* es2    = (float*)(base + 112613376);     // (N)
  float* ed2    = (float*)(base + 112813376);     // (N)
  float* w2e    = (float*)(base + 113013376);     // (E)
  float* invs2  = (float*)(base + 114613376);     // (N)
  int* rowptr   = (int*)(base + 114813376);       // (N+1)
  int* cursor   = (int*)(base + 115013380);       // (N)
  int2* csr2    = (int2*)(base + 115213384);      // (E) {edge, src}
  bf16* B1t     = (bf16*)(base + 118413392);      // (512,288)
  bf16* B2t     = (bf16*)(base + 118708304);      // (128,512)
  bf16* BPt     = (bf16*)(base + 118839376);      // (256,128) -> ends 118,904,912
  int* bsum = (int*)evalw;          // scan scratch (aliases evalw, not yet live)
  int* boff = bsum + 256;

  float* out        = (float*)d_out;
  float* out_logits = out;                          // 32
  float* out_h2     = out + 32;                     // N*128
  float* out_imp    = out + 32 + (size_t)NN * HID;  // E
  float* out_attn   = out_imp + EE;                 // E

  // zero m1/sum1/m2/sum2/deg/stats in one call (ws poisoned 0xAA each call)
  zero_words<<<(553344 + 255) / 256, 256, 0, stream>>>((unsigned int*)m1, 553344);

  // prep: bf16 conversions / transposes
  conv_x<<<(NN * KP1 + 255) / 256, 256, 0, stream>>>(x, xb);
  prep_b1t<<<(C1 * KP1 + 255) / 256, 256, 0, stream>>>(W1, B1t);
  prep_b2t<<<(HID * C1 + 255) / 256, 256, 0, stream>>>(W2, B2t);
  prep_bpt<<<(256 * HID + 255) / 256, 256, 0, stream>>>(ep_w1, BPt);

  // CSR by destination (entries carry {edge, src}); parallel 3-phase scan
  count_kernel<<<(EE + 255) / 256, 256, 0, stream>>>(dstp, deg, EE);
  scan_p1<<<SCAN_NB, 256, 0, stream>>>(deg, bsum);
  scan_p2<<<1, 256, 0, stream>>>(bsum, boff, rowptr + NN);
  scan_p3<<<SCAN_NB, 256, 0, stream>>>(deg, boff, rowptr, cursor);
  scatter_kernel<<<(EE + 255) / 256, 256, 0, stream>>>(srcp, dstp, cursor, csr2, EE);

  // ---- layer 1: one GEMM (all heads), edge-parallel softmax, one aggregate ----
  dim3 g1(C1 / 128, (NN + 127) / 128);
  gemm_mfma<<<g1, 256, 0, stream>>>(xb, B1t, Wh1, NN, KP1, C1);
  edot_all<<<(NN + 3) / 4, 256, 0, stream>>>(Wh1, a_src1, a_dst1, es1, ed1);
  elog1<<<(EE + 255) / 256, 256, 0, stream>>>(srcp, dstp, (const float4*)es1,
                                              (const float4*)ed1, (float4*)evalw, m1);
  ewei1<<<(EE + 255) / 256, 256, 0, stream>>>(dstp, (float4*)evalw, m1, sum1);
  agg1_all<<<(NN + 3) / 4, 256, 0, stream>>>(csr2, rowptr, (const float4*)evalw, sum1,
                                             Wh1, h1);

  elu_stats<<<400, C1, 0, stream>>>(h1, cs1, cq1, NN, C1);
  {
    size_t total = (size_t)NN * C1;
    bn_apply<<<(unsigned)((total + 255) / 256), 256, 0, stream>>>(
        h1, h1, (float*)nullptr, cs1, cq1, bn1_g, bn1_b, C1, total, 1.f / NN);
  }

  // ---- layer 2 ----
  dim3 g2(1, (NN + 127) / 128);
  gemm_mfma<<<g2, 256, 0, stream>>>(h1, B2t, Wh2, NN, C1, HID);
  edot1<<<(NN + 3) / 4, 256, 0, stream>>>(Wh2, a_src2, a_dst2, es2, ed2);
  elog2<<<(EE + 255) / 256, 256, 0, stream>>>(srcp, dstp, es2, ed2, w2e, m2);
  ewei2<<<(EE + 255) / 256, 256, 0, stream>>>(dstp, w2e, m2, sum2);
  agg2_all<<<(NN + 3) / 4, 256, 0, stream>>>(csr2, rowptr, w2e, sum2, Wh2, h2p, invs2);
  attn_edge<<<(EE + 255) / 256, 256, 0, stream>>>(dstp, w2e, invs2, out_attn);

  elu_stats<<<400, HID, 0, stream>>>(h2p, cs2, cq2, NN, HID);
  {
    size_t total = (size_t)NN * HID;
    bn_apply<<<(unsigned)((total + 255) / 256), 256, 0, stream>>>(
        h2p, h2, out_h2, cs2, cq2, bn2_g, bn2_b, HID, total, 1.f / NN);
  }

  // ---- heads ----
  pool_kernel<<<(NN + 31) / 32, 256, 0, stream>>>(h2, batch, pooled);
  cnt_kernel<<<1, 64, 0, stream>>>(batch, cnt);
  cls_kernel<<<1, 128, 0, stream>>>(pooled, cnt, cls_w1, cls_b1, cls_w2, cls_b2, out_logits);

  dim3 gpq(2, (NN + 127) / 128);
  gemm_mfma<<<gpq, 256, 0, stream>>>(h2, BPt, PQ, NN, HID, 256);
  eimp_kernel<<<(EE + 3) / 4, 256, 0, stream>>>(srcp, dstp, PQ, ep_b1, ep_w2, ep_b2, out_imp);
}

// Round 8
// 823.468 us; speedup vs baseline: 2.6180x; 1.1423x over previous
//
#include <hip/hip_runtime.h>
#include <hip/hip_bf16.h>
#include <math.h>

typedef __hip_bfloat16 bf16;
typedef __bf16 bf16x8 __attribute__((ext_vector_type(8)));
typedef __bf16 bf16x2v __attribute__((ext_vector_type(2)));
typedef float f32x4 __attribute__((ext_vector_type(4)));

#define NN 50000
#define EE 400000
#define FIN 262
#define KP1 288   /* FIN padded to multiple of 32 */
#define HID 128
#define NH 4
#define C1 512   /* HID*NH */
#define NGR 16
#define SCAN_NB ((NN + 255) / 256)   /* 196 */

__device__ __forceinline__ float b2f(bf16 x){ return __bfloat162float(x); }
__device__ __forceinline__ bf16 f2b(float x){ return __float2bfloat16(x); }

__global__ void zero_words(unsigned int* __restrict__ p, int n) {
  int i = blockIdx.x * 256 + threadIdx.x;
  if (i < n) p[i] = 0u;
}

// ================= MFMA GEMM: C(M,N) = A(M,K) @ B(K,N) =================
__global__ __launch_bounds__(256)
void gemm_mfma(const bf16* __restrict__ A, const bf16* __restrict__ Bt,
               bf16* __restrict__ C, int M, int K, int Ncols) {
  __shared__ __align__(16) __bf16 As[128 * 40];  // +8 pad: 2-way banks only (free)
  __shared__ __align__(16) __bf16 Bs[128 * 40];
  int bm = blockIdx.y * 128, bn = blockIdx.x * 128;
  int tid = threadIdx.x;
  int wave = tid >> 6, lane = tid & 63;
  int quad = lane >> 4, l16 = lane & 15;
  int wm = (wave >> 1) * 64, wn = (wave & 1) * 64;
  f32x4 acc[4][4];
  #pragma unroll
  for (int i = 0; i < 4; ++i)
    #pragma unroll
    for (int j = 0; j < 4; ++j)
      acc[i][j] = (f32x4){0.f, 0.f, 0.f, 0.f};

  for (int k0 = 0; k0 < K; k0 += 32) {
    #pragma unroll
    for (int l = 0; l < 2; ++l) {
      int e = l * 2048 + tid * 8;
      int row = e >> 5, col = e & 31;           // 128 rows x 32 cols
      uint4 va = {0u, 0u, 0u, 0u};
      int gm = bm + row;
      if (gm < M) va = *(const uint4*)(A + (size_t)gm * K + k0 + col);
      *(uint4*)(&As[row * 40 + col]) = va;
      uint4 vb = {0u, 0u, 0u, 0u};
      int gn = bn + row;
      if (gn < Ncols) vb = *(const uint4*)(Bt + (size_t)gn * K + k0 + col);
      *(uint4*)(&Bs[row * 40 + col]) = vb;
    }
    __syncthreads();
    bf16x8 af[4], bf_[4];
    #pragma unroll
    for (int i = 0; i < 4; ++i)
      af[i] = *(const bf16x8*)(&As[(wm + i * 16 + l16) * 40 + quad * 8]);
    #pragma unroll
    for (int j = 0; j < 4; ++j)
      bf_[j] = *(const bf16x8*)(&Bs[(wn + j * 16 + l16) * 40 + quad * 8]);
    #pragma unroll
    for (int i = 0; i < 4; ++i)
      #pragma unroll
      for (int j = 0; j < 4; ++j)
        acc[i][j] = __builtin_amdgcn_mfma_f32_16x16x32_bf16(af[i], bf_[j], acc[i][j], 0, 0, 0);
    __syncthreads();
  }
  #pragma unroll
  for (int i = 0; i < 4; ++i) {
    #pragma unroll
    for (int r = 0; r < 4; ++r) {
      int gm = bm + wm + i * 16 + quad * 4 + r;
      if (gm >= M) continue;
      #pragma unroll
      for (int j = 0; j < 4; ++j) {
        int gn = bn + wn + j * 16 + l16;
        C[(size_t)gm * Ncols + gn] = f2b(acc[i][j][r]);
      }
    }
  }
}

// ---- prep kernels ----
__global__ void conv_x(const float* __restrict__ x, bf16* __restrict__ xb) {
  int i = blockIdx.x * 256 + threadIdx.x;
  if (i >= NN * KP1) return;
  int row = i / KP1, col = i - row * KP1;
  xb[i] = (col < FIN) ? f2b(x[(size_t)row * FIN + col]) : f2b(0.f);
}
__global__ void prep_b1t(const float* __restrict__ W1, bf16* __restrict__ B1t) {
  int i = blockIdx.x * 256 + threadIdx.x;
  if (i >= C1 * KP1) return;
  int n = i / KP1, k = i - n * KP1;   // n = h*128 + o
  int h = n >> 7, o = n & 127;
  B1t[i] = (k < FIN) ? f2b(W1[((size_t)h * FIN + k) * HID + o]) : f2b(0.f);
}
__global__ void prep_b2t(const float* __restrict__ W2, bf16* __restrict__ B2t) {
  int i = blockIdx.x * 256 + threadIdx.x;
  if (i >= HID * C1) return;
  int n = i >> 9, k = i & 511;
  B2t[i] = f2b(W2[(size_t)k * HID + n]);
}
__global__ void prep_bpt(const float* __restrict__ epw1, bf16* __restrict__ BPt) {
  int i = blockIdx.x * 256 + threadIdx.x;
  if (i >= 256 * HID) return;
  int n = i >> 7, k = i & 127;
  float v = (n < 128) ? epw1[(size_t)k * HID + n] : epw1[(size_t)(128 + k) * HID + (n - 128)];
  BPt[i] = f2b(v);
}

// ---- edot over all 4 heads: wave per node ----
__global__ void edot_all(const bf16* __restrict__ Wh1, const float* __restrict__ av,
                         const float* __restrict__ bv, float* __restrict__ es1,
                         float* __restrict__ ed1) {
  int wid = threadIdx.x >> 6, lane = threadIdx.x & 63;
  int n = blockIdx.x * 4 + wid;
  if (n >= NN) return;
  int h = lane >> 4, c16 = lane & 15;
  int fbase = h * HID + c16 * 8;
  bf16x8 r = *(const bf16x8*)(Wh1 + (size_t)n * C1 + fbase);
  float s1 = 0.f, s2 = 0.f;
  #pragma unroll
  for (int j = 0; j < 8; ++j) {
    float rv = (float)r[j];
    s1 += rv * av[fbase + j];
    s2 += rv * bv[fbase + j];
  }
  #pragma unroll
  for (int off = 8; off > 0; off >>= 1) {
    s1 += __shfl_xor(s1, off);
    s2 += __shfl_xor(s2, off);
  }
  if (c16 == 0) { es1[n * 4 + h] = s1; ed1[n * 4 + h] = s2; }
}

// per-node dot (H=1, 128-wide); one wave per node
__global__ void edot1(const bf16* __restrict__ Wh, const float* __restrict__ av,
                      const float* __restrict__ bv, float* __restrict__ es,
                      float* __restrict__ ed) {
  int wid = threadIdx.x >> 6, lane = threadIdx.x & 63;
  int r = blockIdx.x * 4 + wid;
  if (r >= NN) return;
  const bf16* row = Wh + (size_t)r * HID;
  float w0 = b2f(row[lane]), w1 = b2f(row[lane + 64]);
  float s1 = w0 * av[lane] + w1 * av[lane + 64];
  float s2 = w0 * bv[lane] + w1 * bv[lane + 64];
  #pragma unroll
  for (int off = 32; off > 0; off >>= 1) {
    s1 += __shfl_xor(s1, off);
    s2 += __shfl_xor(s2, off);
  }
  if (lane == 0) { es[r] = s1; ed[r] = s2; }
}

// ---------------- CSR build ----------------
__global__ void count_kernel(const int* __restrict__ dst, int* __restrict__ deg, int E) {
  int e = blockIdx.x * blockDim.x + threadIdx.x;
  if (e >= E) return;
  int d = dst[e];
  if ((unsigned)d < NN) atomicAdd(&deg[d], 1);
}

// -- parallel 3-phase exclusive scan of deg --
__global__ void scan_p1(const int* __restrict__ deg, int* __restrict__ bsum) {
  __shared__ int s[256];
  int t = threadIdx.x;
  int i = blockIdx.x * 256 + t;
  s[t] = (i < NN) ? deg[i] : 0;
  __syncthreads();
  #pragma unroll
  for (int off = 128; off > 0; off >>= 1) {
    if (t < off) s[t] += s[t + off];
    __syncthreads();
  }
  if (t == 0) bsum[blockIdx.x] = s[0];
}
__global__ void scan_p2(const int* __restrict__ bsum, int* __restrict__ boff,
                        int* __restrict__ total_out) {
  __shared__ int s[256];
  int t = threadIdx.x;
  s[t] = (t < SCAN_NB) ? bsum[t] : 0;
  __syncthreads();
  if (t == 0) {
    int r = 0;
    for (int i = 0; i < SCAN_NB; ++i) { int v = s[i]; s[i] = r; r += v; }
    total_out[0] = r;   // rowptr[NN]
  }
  __syncthreads();
  if (t < SCAN_NB) boff[t] = s[t];
}
__global__ void scan_p3(const int* __restrict__ deg, const int* __restrict__ boff,
                        int* __restrict__ rowptr, int* __restrict__ cursor) {
  __shared__ int s[256];
  int t = threadIdx.x;
  int i = blockIdx.x * 256 + t;
  int v = (i < NN) ? deg[i] : 0;
  s[t] = v;
  __syncthreads();
  #pragma unroll
  for (int off = 1; off < 256; off <<= 1) {
    int add = (t >= off) ? s[t - off] : 0;
    __syncthreads();
    s[t] += add;
    __syncthreads();
  }
  if (i < NN) {
    int pos = boff[blockIdx.x] + s[t] - v;   // exclusive
    rowptr[i] = pos;
    cursor[i] = pos;
  }
}

// csr entry = {edge id, src node}
__global__ void scatter_kernel(const int* __restrict__ src, const int* __restrict__ dst,
                               int* __restrict__ cursor, int2* __restrict__ csr2, int E) {
  int e = blockIdx.x * blockDim.x + threadIdx.x;
  if (e >= E) return;
  int d = dst[e];
  if ((unsigned)d >= NN) return;
  int s = src[e]; if ((unsigned)s >= NN) s = 0;
  int p = atomicAdd(&cursor[d], 1);
  if ((unsigned)p < (unsigned)E) csr2[p] = make_int2(e, s);
}

// ---- layer-1 edge logits (4 heads), pure coalesced store (NO atomics) ----
__global__ void elog1(const int* __restrict__ src, const int* __restrict__ dst,
                      const float4* __restrict__ es1, const float4* __restrict__ ed1,
                      float4* __restrict__ evalw) {
  int e = blockIdx.x * 256 + threadIdx.x;
  if (e >= EE) return;
  int s = src[e]; if ((unsigned)s >= NN) s = 0;
  int d = dst[e]; if ((unsigned)d >= NN) d = 0;
  float4 a = es1[s], b = ed1[d];
  float v[4] = {a.x + b.x, a.y + b.y, a.z + b.z, a.w + b.w};
  #pragma unroll
  for (int h = 0; h < 4; ++h) v[h] = v[h] >= 0.f ? v[h] : 0.2f * v[h];
  evalw[e] = make_float4(v[0], v[1], v[2], v[3]);
}

// ---- layer-1 fused softmax+aggregate: wave per node, two passes, no atomics ----
__global__ __launch_bounds__(256)
void agg1_all(const int2* __restrict__ csr2, const int* __restrict__ rowptr,
              const float4* __restrict__ w4arr, const bf16* __restrict__ Wh1,
              bf16* __restrict__ h1) {
  int wid = threadIdx.x >> 6, lane = threadIdx.x & 63;
  int node = blockIdx.x * 4 + wid;
  if (node >= NN) return;
  int b = rowptr[node], e = rowptr[node + 1];
  if (b < 0) b = 0; if (e > EE) e = EE;
  int h = lane >> 4;
  // pass 1: per-head max (e_max = max(seg_max, 0) -> init 0)
  float m = 0.f;
  for (int j = b; j < e; ++j) {
    int2 c = csr2[j];
    float4 w4 = w4arr[c.x];
    float v = h == 0 ? w4.x : h == 1 ? w4.y : h == 2 ? w4.z : w4.w;
    m = fmaxf(m, v);
  }
  // pass 2: exp, sum, aggregate
  float sum = 0.f;
  float acc[8] = {};
  for (int j = b; j < e; ++j) {
    int2 c = csr2[j];
    float4 w4 = w4arr[c.x];
    float v = h == 0 ? w4.x : h == 1 ? w4.y : h == 2 ? w4.z : w4.w;
    float p = expf(v - m);
    sum += p;
    bf16x8 r = *(const bf16x8*)(Wh1 + (size_t)c.y * C1 + lane * 8);
    #pragma unroll
    for (int k = 0; k < 8; ++k) acc[k] += p * (float)r[k];
  }
  float scale = 1.f / (sum + 1e-8f);
  bf16x8 o;
  #pragma unroll
  for (int k = 0; k < 8; ++k) o[k] = (__bf16)(acc[k] * scale);
  *(bf16x8*)(h1 + (size_t)node * C1 + lane * 8) = o;
}

// ---- layer-2 edge logits (H=1), pure store ----
__global__ void elog2(const int* __restrict__ src, const int* __restrict__ dst,
                      const float* __restrict__ es2, const float* __restrict__ ed2,
                      float* __restrict__ w2e) {
  int e = blockIdx.x * 256 + threadIdx.x;
  if (e >= EE) return;
  int s = src[e]; if ((unsigned)s >= NN) s = 0;
  int d = dst[e]; if ((unsigned)d >= NN) d = 0;
  float v = es2[s] + ed2[d];
  v = v >= 0.f ? v : 0.2f * v;
  w2e[e] = v;
}

// ---- layer-2 fused softmax+aggregate: wave per node, two passes, no atomics ----
__global__ __launch_bounds__(256)
void agg2_all(const int2* __restrict__ csr2, const int* __restrict__ rowptr,
              const float* __restrict__ w2e, const bf16* __restrict__ Wh2,
              bf16* __restrict__ h2p, float* __restrict__ invs2,
              float* __restrict__ m2f) {
  int wid = threadIdx.x >> 6, lane = threadIdx.x & 63;
  int node = blockIdx.x * 4 + wid;
  if (node >= NN) return;
  int b = rowptr[node], e = rowptr[node + 1];
  if (b < 0) b = 0; if (e > EE) e = EE;
  float m = 0.f;
  for (int j = b; j < e; ++j) m = fmaxf(m, w2e[csr2[j].x]);
  float sum = 0.f, a0 = 0.f, a1 = 0.f;
  for (int j = b; j < e; ++j) {
    int2 c = csr2[j];
    float p = expf(w2e[c.x] - m);
    sum += p;
    bf16x2v r = *(const bf16x2v*)(Wh2 + (size_t)c.y * HID + lane * 2);
    a0 += p * (float)r[0];
    a1 += p * (float)r[1];
  }
  float scale = 1.f / (sum + 1e-8f);
  bf16x2v o;
  o[0] = (__bf16)(a0 * scale);
  o[1] = (__bf16)(a1 * scale);
  *(bf16x2v*)(h2p + (size_t)node * HID + lane * 2) = o;
  if (lane == 0) { invs2[node] = scale; m2f[node] = m; }
}

// ---- attention output (edge-parallel, recompute exp) ----
__global__ void attn_edge(const int* __restrict__ dst, const float* __restrict__ w2e,
                          const float* __restrict__ invs2, const float* __restrict__ m2f,
                          float* __restrict__ attn_out) {
  int e = blockIdx.x * 256 + threadIdx.x;
  if (e >= EE) return;
  int d = dst[e]; if ((unsigned)d >= NN) d = 0;
  attn_out[e] = expf(w2e[e] - m2f[d]) * invs2[d];
}

// ---- ELU in place (bf16) + per-column fp32 sum/sumsq; blockDim == C ----
__global__ void elu_stats(bf16* __restrict__ X, float* __restrict__ cs, float* __restrict__ cq,
                          int Nrows, int C) {
  int c = threadIdx.x;
  int rpb = (Nrows + gridDim.x - 1) / gridDim.x;
  int r0 = blockIdx.x * rpb, r1 = min(r0 + rpb, Nrows);
  float s = 0.f, s2 = 0.f;
  for (int r = r0; r < r1; ++r) {
    size_t idx = (size_t)r * C + c;
    float v = b2f(X[idx]);
    v = v > 0.f ? v : expm1f(v);
    X[idx] = f2b(v);
    s += v; s2 += v * v;
  }
  atomicAdd(&cs[c], s);
  atomicAdd(&cq[c], s2);
}

__global__ void bn_apply(const bf16* __restrict__ in, bf16* __restrict__ out,
                         float* __restrict__ out2,
                         const float* __restrict__ cs, const float* __restrict__ cq,
                         const float* __restrict__ gamma, const float* __restrict__ beta,
                         int C, size_t total, float invN) {
  size_t i = (size_t)blockIdx.x * blockDim.x + threadIdx.x;
  if (i >= total) return;
  int c = (int)(i % C);
  float mu = cs[c] * invN;
  float var = cq[c] * invN - mu * mu;
  float v = (b2f(in[i]) - mu) * rsqrtf(fmaxf(var, 0.f) + 1e-5f) * gamma[c] + beta[c];
  out[i] = f2b(v);
  if (out2) out2[i] = v;
}

// ---- global mean pool: 32 rows/block, register-accumulate per graph run ----
__global__ __launch_bounds__(256)
void pool_kernel(const bf16* __restrict__ h2, const int* __restrict__ batch,
                 float* __restrict__ pooled) {
  int t = threadIdx.x;
  int f = t & 127, half = t >> 7;
  int r0 = blockIdx.x * 32;
  int g_cur = -1;
  float acc = 0.f;
  #pragma unroll
  for (int i = 0; i < 16; ++i) {
    int r = r0 + half + 2 * i;
    if (r >= NN) break;
    int g = batch[r]; if ((unsigned)g >= NGR) g = 0;
    float v = b2f(h2[(size_t)r * HID + f]);
    if (g != g_cur) {
      if (g_cur >= 0) atomicAdd(&pooled[g_cur * HID + f], acc);
      g_cur = g; acc = 0.f;
    }
    acc += v;
  }
  if (g_cur >= 0) atomicAdd(&pooled[g_cur * HID + f], acc);
}

// ---- per-graph counts via binary search on sorted batch ----
__global__ void cnt_kernel(const int* __restrict__ batch, float* __restrict__ cnt) {
  int g = threadIdx.x;
  if (g >= NGR) return;
  int a = 0, b = NN;
  while (a < b) { int m = (a + b) >> 1; if (batch[m] < g) a = m + 1; else b = m; }
  int lb = a;
  a = 0; b = NN;
  while (a < b) { int m = (a + b) >> 1; if (batch[m] <= g) a = m + 1; else b = m; }
  cnt[g] = (float)(a - lb);
}

// ---- classifier (tiny, single block) ----
__global__ void cls_kernel(const float* __restrict__ pooled, const float* __restrict__ cnt,
                           const float* __restrict__ w1, const float* __restrict__ b1,
                           const float* __restrict__ w2, const float* __restrict__ b2,
                           float* __restrict__ out) {
  __shared__ float repr[NGR * HID];
  __shared__ float hid[NGR * 64];
  int t = threadIdx.x;  // 128
  for (int i = t; i < NGR * HID; i += 128) {
    int g = i >> 7;
    repr[i] = pooled[i] / fmaxf(cnt[g], 1.f);
  }
  __syncthreads();
  for (int i = t; i < NGR * 64; i += 128) {
    int g = i >> 6, j = i & 63;
    float s = b1[j];
    for (int c = 0; c < HID; ++c) s += repr[g * HID + c] * w1[c * 64 + j];
    hid[i] = fmaxf(s, 0.f);
  }
  __syncthreads();
  if (t < NGR * 2) {
    int g = t >> 1, k = t & 1;
    float s = b2[k];
    for (int j = 0; j < 64; ++j) s += hid[g * 64 + j] * w2[j * 2 + k];
    out[t] = s;
  }
}

// ---- edge importance from fused PQ (N,256) ----
__global__ void eimp_kernel(const int* __restrict__ src, const int* __restrict__ dstp,
                            const bf16* __restrict__ PQ,
                            const float* __restrict__ b1, const float* __restrict__ w2,
                            const float* __restrict__ b2, float* __restrict__ out) {
  int wid = threadIdx.x >> 6, lane = threadIdx.x & 63;
  int e = blockIdx.x * 4 + wid;
  if (e >= EE) return;
  int s = src[e]; if ((unsigned)s >= NN) s = 0;
  int d = dstp[e]; if ((unsigned)d >= NN) d = 0;
  bf16x2v p2 = *(const bf16x2v*)(PQ + (size_t)s * 256 + lane * 2);
  bf16x2v q2 = *(const bf16x2v*)(PQ + (size_t)d * 256 + 128 + lane * 2);
  float acc = 0.f;
  #pragma unroll
  for (int r = 0; r < 2; ++r) {
    int j = lane * 2 + r;
    float hh = (float)p2[r] + (float)q2[r] + b1[j];
    hh = fmaxf(hh, 0.f);
    acc += hh * w2[j];
  }
  #pragma unroll
  for (int off = 32; off > 0; off >>= 1) acc += __shfl_xor(acc, off);
  if (lane == 0) {
    float z = acc + b2[0];
    out[e] = 1.f / (1.f + expf(-z));
  }
}

extern "C" void kernel_launch(void* const* d_in, const int* in_sizes, int n_in,
                              void* d_out, int out_size, void* d_ws, size_t ws_size,
                              hipStream_t stream) {
  const float* x      = (const float*)d_in[0];
  const int*   ei     = (const int*)d_in[1];
  const int*   batch  = (const int*)d_in[2];
  const float* W1     = (const float*)d_in[3];
  const float* a_src1 = (const float*)d_in[4];
  const float* a_dst1 = (const float*)d_in[5];
  const float* W2     = (const float*)d_in[6];
  const float* a_src2 = (const float*)d_in[7];
  const float* a_dst2 = (const float*)d_in[8];
  const float* bn1_g  = (const float*)d_in[9];
  const float* bn1_b  = (const float*)d_in[10];
  const float* bn2_g  = (const float*)d_in[11];
  const float* bn2_b  = (const float*)d_in[12];
  const float* cls_w1 = (const float*)d_in[13];
  const float* cls_b1 = (const float*)d_in[14];
  const float* cls_w2 = (const float*)d_in[15];
  const float* cls_b2 = (const float*)d_in[16];
  const float* ep_w1  = (const float*)d_in[17];
  const float* ep_b1  = (const float*)d_in[18];
  const float* ep_w2  = (const float*)d_in[19];
  const float* ep_b2  = (const float*)d_in[20];

  const int* srcp = ei;
  const int* dstp = ei + EE;

  // ---- workspace layout (bytes), peak ~118.9 MB, hazard-checked ----
  char* base = (char*)d_ws;
  bf16* xb  = (bf16*)(base);
  bf16* h1  = (bf16*)(base);
  bf16* Wh1 = (bf16*)(base + 51200000);
  bf16* Wh2 = (bf16*)(base + 51200000);   // (N,128) after agg1 (Wh1 dead)
  bf16* h2p = (bf16*)(base + 64000000);   // (N,128)
  bf16* h2  = (bf16*)(base + 76800000);   // (N,128)
  bf16* PQ  = (bf16*)(base + 51200000);   // (N,256) after bn2 (Wh2,h2p dead)
  float* m2f    = (float*)(base + 104000000);     // (N) layer-2 softmax max
  int* deg      = (int*)(base + 104400000);       // (N)  [adjacent to stats: one zero call]
  float* stats  = (float*)(base + 104600000);     // 3344 floats
  float* cs1 = stats,        *cq1 = stats + 512;
  float* cs2 = stats + 1024, *cq2 = stats + 1152;
  float* pooled = stats + 1280;                   // 16*128
  float* cnt    = stats + 3328;                   // 16
  float* es1    = (float*)(base + 104613376);     // (N,4)
  float* ed1    = (float*)(base + 105413376);     // (N,4)
  float* evalw  = (float*)(base + 106213376);     // (E,4) logits
  float* es2    = (float*)(base + 112613376);     // (N)
  float* ed2    = (float*)(base + 112813376);     // (N)
  float* w2e    = (float*)(base + 113013376);     // (E) logits
  float* invs2  = (float*)(base + 114613376);     // (N)
  int* rowptr   = (int*)(base + 114813376);       // (N+1)
  int* cursor   = (int*)(base + 115013380);       // (N)
  int2* csr2    = (int2*)(base + 115213384);      // (E) {edge, src}
  bf16* B1t     = (bf16*)(base + 118413392);      // (512,288)
  bf16* B2t     = (bf16*)(base + 118708304);      // (128,512)
  bf16* BPt     = (bf16*)(base + 118839376);      // (256,128) -> ends 118,904,912
  int* bsum = (int*)evalw;          // scan scratch (aliases evalw, not yet live)
  int* boff = bsum + 256;

  float* out        = (float*)d_out;
  float* out_logits = out;                          // 32
  float* out_h2     = out + 32;                     // N*128
  float* out_imp    = out + 32 + (size_t)NN * HID;  // E
  float* out_attn   = out_imp + EE;                 // E

  // zero deg+stats in one call (adjacent; 53,344 words)
  zero_words<<<(53344 + 255) / 256, 256, 0, stream>>>((unsigned int*)deg, 53344);

  // prep: bf16 conversions / transposes
  conv_x<<<(NN * KP1 + 255) / 256, 256, 0, stream>>>(x, xb);
  prep_b1t<<<(C1 * KP1 + 255) / 256, 256, 0, stream>>>(W1, B1t);
  prep_b2t<<<(HID * C1 + 255) / 256, 256, 0, stream>>>(W2, B2t);
  prep_bpt<<<(256 * HID + 255) / 256, 256, 0, stream>>>(ep_w1, BPt);

  // CSR by destination (entries carry {edge, src}); parallel 3-phase scan
  count_kernel<<<(EE + 255) / 256, 256, 0, stream>>>(dstp, deg, EE);
  scan_p1<<<SCAN_NB, 256, 0, stream>>>(deg, bsum);
  scan_p2<<<1, 256, 0, stream>>>(bsum, boff, rowptr + NN);
  scan_p3<<<SCAN_NB, 256, 0, stream>>>(deg, boff, rowptr, cursor);
  scatter_kernel<<<(EE + 255) / 256, 256, 0, stream>>>(srcp, dstp, cursor, csr2, EE);

  // ---- layer 1: one GEMM (all heads), coalesced logits, fused softmax-aggregate ----
  dim3 g1(C1 / 128, (NN + 127) / 128);
  gemm_mfma<<<g1, 256, 0, stream>>>(xb, B1t, Wh1, NN, KP1, C1);
  edot_all<<<(NN + 3) / 4, 256, 0, stream>>>(Wh1, a_src1, a_dst1, es1, ed1);
  elog1<<<(EE + 255) / 256, 256, 0, stream>>>(srcp, dstp, (const float4*)es1,
                                              (const float4*)ed1, (float4*)evalw);
  agg1_all<<<(NN + 3) / 4, 256, 0, stream>>>(csr2, rowptr, (const float4*)evalw, Wh1, h1);

  elu_stats<<<400, C1, 0, stream>>>(h1, cs1, cq1, NN, C1);
  {
    size_t total = (size_t)NN * C1;
    bn_apply<<<(unsigned)((total + 255) / 256), 256, 0, stream>>>(
        h1, h1, (float*)nullptr, cs1, cq1, bn1_g, bn1_b, C1, total, 1.f / NN);
  }

  // ---- layer 2 ----
  dim3 g2(1, (NN + 127) / 128);
  gemm_mfma<<<g2, 256, 0, stream>>>(h1, B2t, Wh2, NN, C1, HID);
  edot1<<<(NN + 3) / 4, 256, 0, stream>>>(Wh2, a_src2, a_dst2, es2, ed2);
  elog2<<<(EE + 255) / 256, 256, 0, stream>>>(srcp, dstp, es2, ed2, w2e);
  agg2_all<<<(NN + 3) / 4, 256, 0, stream>>>(csr2, rowptr, w2e, Wh2, h2p, invs2, m2f);
  attn_edge<<<(EE + 255) / 256, 256, 0, stream>>>(dstp, w2e, invs2, m2f, out_attn);

  elu_stats<<<400, HID, 0, stream>>>(h2p, cs2, cq2, NN, HID);
  {
    size_t total = (size_t)NN * HID;
    bn_apply<<<(unsigned)((total + 255) / 256), 256, 0, stream>>>(
        h2p, h2, out_h2, cs2, cq2, bn2_g, bn2_b, HID, total, 1.f / NN);
  }

  // ---- heads ----
  pool_kernel<<<(NN + 31) / 32, 256, 0, stream>>>(h2, batch, pooled);
  cnt_kernel<<<1, 64, 0, stream>>>(batch, cnt);
  cls_kernel<<<1, 128, 0, stream>>>(pooled, cnt, cls_w1, cls_b1, cls_w2, cls_b2, out_logits);

  dim3 gpq(2, (NN + 127) / 128);
  gemm_mfma<<<gpq, 256, 0, stream>>>(h2, BPt, PQ, NN, HID, 256);
  eimp_kernel<<<(EE + 3) / 4, 256, 0, stream>>>(srcp, dstp, PQ, ep_b1, ep_w2, ep_b2, out_imp);
}

// Round 9
// 746.644 us; speedup vs baseline: 2.8874x; 1.1029x over previous
//
#include <hip/hip_runtime.h>
#include <hip/hip_bf16.h>
#include <math.h>

typedef __hip_bfloat16 bf16;
typedef __bf16 bf16x8 __attribute__((ext_vector_type(8)));
typedef __bf16 bf16x2v __attribute__((ext_vector_type(2)));
typedef float f32x4 __attribute__((ext_vector_type(4)));

#define NN 50000
#define EE 400000
#define FIN 262
#define KP1 288   /* FIN padded to multiple of 32 */
#define HID 128
#define NH 4
#define C1 512   /* HID*NH */
#define NGR 16
#define SCAN_NB ((NN + 255) / 256)   /* 196 */

__device__ __forceinline__ float b2f(bf16 x){ return __bfloat162float(x); }
__device__ __forceinline__ bf16 f2b(float x){ return __float2bfloat16(x); }

__global__ void zero_words(unsigned int* __restrict__ p, int n) {
  int i = blockIdx.x * 256 + threadIdx.x;
  if (i < n) p[i] = 0u;
}

// ================= MFMA GEMM: C(M,N) = A(M,K) @ B(K,N) =================
__global__ __launch_bounds__(256)
void gemm_mfma(const bf16* __restrict__ A, const bf16* __restrict__ Bt,
               bf16* __restrict__ C, int M, int K, int Ncols) {
  __shared__ __align__(16) __bf16 As[128 * 40];  // +8 pad: 2-way banks only (free)
  __shared__ __align__(16) __bf16 Bs[128 * 40];
  int bm = blockIdx.y * 128, bn = blockIdx.x * 128;
  int tid = threadIdx.x;
  int wave = tid >> 6, lane = tid & 63;
  int quad = lane >> 4, l16 = lane & 15;
  int wm = (wave >> 1) * 64, wn = (wave & 1) * 64;
  f32x4 acc[4][4];
  #pragma unroll
  for (int i = 0; i < 4; ++i)
    #pragma unroll
    for (int j = 0; j < 4; ++j)
      acc[i][j] = (f32x4){0.f, 0.f, 0.f, 0.f};

  for (int k0 = 0; k0 < K; k0 += 32) {
    #pragma unroll
    for (int l = 0; l < 2; ++l) {
      int e = l * 2048 + tid * 8;
      int row = e >> 5, col = e & 31;           // 128 rows x 32 cols
      uint4 va = {0u, 0u, 0u, 0u};
      int gm = bm + row;
      if (gm < M) va = *(const uint4*)(A + (size_t)gm * K + k0 + col);
      *(uint4*)(&As[row * 40 + col]) = va;
      uint4 vb = {0u, 0u, 0u, 0u};
      int gn = bn + row;
      if (gn < Ncols) vb = *(const uint4*)(Bt + (size_t)gn * K + k0 + col);
      *(uint4*)(&Bs[row * 40 + col]) = vb;
    }
    __syncthreads();
    bf16x8 af[4], bf_[4];
    #pragma unroll
    for (int i = 0; i < 4; ++i)
      af[i] = *(const bf16x8*)(&As[(wm + i * 16 + l16) * 40 + quad * 8]);
    #pragma unroll
    for (int j = 0; j < 4; ++j)
      bf_[j] = *(const bf16x8*)(&Bs[(wn + j * 16 + l16) * 40 + quad * 8]);
    #pragma unroll
    for (int i = 0; i < 4; ++i)
      #pragma unroll
      for (int j = 0; j < 4; ++j)
        acc[i][j] = __builtin_amdgcn_mfma_f32_16x16x32_bf16(af[i], bf_[j], acc[i][j], 0, 0, 0);
    __syncthreads();
  }
  #pragma unroll
  for (int i = 0; i < 4; ++i) {
    #pragma unroll
    for (int r = 0; r < 4; ++r) {
      int gm = bm + wm + i * 16 + quad * 4 + r;
      if (gm >= M) continue;
      #pragma unroll
      for (int j = 0; j < 4; ++j) {
        int gn = bn + wn + j * 16 + l16;
        C[(size_t)gm * Ncols + gn] = f2b(acc[i][j][r]);
      }
    }
  }
}

// ---- prep kernels ----
__global__ void conv_x(const float* __restrict__ x, bf16* __restrict__ xb) {
  int i = blockIdx.x * 256 + threadIdx.x;
  if (i >= NN * KP1) return;
  int row = i / KP1, col = i - row * KP1;
  xb[i] = (col < FIN) ? f2b(x[(size_t)row * FIN + col]) : f2b(0.f);
}
__global__ void prep_b1t(const float* __restrict__ W1, bf16* __restrict__ B1t) {
  int i = blockIdx.x * 256 + threadIdx.x;
  if (i >= C1 * KP1) return;
  int n = i / KP1, k = i - n * KP1;   // n = h*128 + o
  int h = n >> 7, o = n & 127;
  B1t[i] = (k < FIN) ? f2b(W1[((size_t)h * FIN + k) * HID + o]) : f2b(0.f);
}
__global__ void prep_b2t(const float* __restrict__ W2, bf16* __restrict__ B2t) {
  int i = blockIdx.x * 256 + threadIdx.x;
  if (i >= HID * C1) return;
  int n = i >> 9, k = i & 511;
  B2t[i] = f2b(W2[(size_t)k * HID + n]);
}
__global__ void prep_bpt(const float* __restrict__ epw1, bf16* __restrict__ BPt) {
  int i = blockIdx.x * 256 + threadIdx.x;
  if (i >= 256 * HID) return;
  int n = i >> 7, k = i & 127;
  float v = (n < 128) ? epw1[(size_t)k * HID + n] : epw1[(size_t)(128 + k) * HID + (n - 128)];
  BPt[i] = f2b(v);
}

// ---- edot over all 4 heads: wave per node ----
__global__ void edot_all(const bf16* __restrict__ Wh1, const float* __restrict__ av,
                         const float* __restrict__ bv, float* __restrict__ es1,
                         float* __restrict__ ed1) {
  int wid = threadIdx.x >> 6, lane = threadIdx.x & 63;
  int n = blockIdx.x * 4 + wid;
  if (n >= NN) return;
  int h = lane >> 4, c16 = lane & 15;
  int fbase = h * HID + c16 * 8;
  bf16x8 r = *(const bf16x8*)(Wh1 + (size_t)n * C1 + fbase);
  float s1 = 0.f, s2 = 0.f;
  #pragma unroll
  for (int j = 0; j < 8; ++j) {
    float rv = (float)r[j];
    s1 += rv * av[fbase + j];
    s2 += rv * bv[fbase + j];
  }
  #pragma unroll
  for (int off = 8; off > 0; off >>= 1) {
    s1 += __shfl_xor(s1, off);
    s2 += __shfl_xor(s2, off);
  }
  if (c16 == 0) { es1[n * 4 + h] = s1; ed1[n * 4 + h] = s2; }
}

// per-node dot (H=1, 128-wide); one wave per node
__global__ void edot1(const bf16* __restrict__ Wh, const float* __restrict__ av,
                      const float* __restrict__ bv, float* __restrict__ es,
                      float* __restrict__ ed) {
  int wid = threadIdx.x >> 6, lane = threadIdx.x & 63;
  int r = blockIdx.x * 4 + wid;
  if (r >= NN) return;
  const bf16* row = Wh + (size_t)r * HID;
  float w0 = b2f(row[lane]), w1 = b2f(row[lane + 64]);
  float s1 = w0 * av[lane] + w1 * av[lane + 64];
  float s2 = w0 * bv[lane] + w1 * bv[lane + 64];
  #pragma unroll
  for (int off = 32; off > 0; off >>= 1) {
    s1 += __shfl_xor(s1, off);
    s2 += __shfl_xor(s2, off);
  }
  if (lane == 0) { es[r] = s1; ed[r] = s2; }
}

// ---------------- CSR build ----------------
__global__ void count_kernel(const int* __restrict__ dst, int* __restrict__ deg, int E) {
  int e = blockIdx.x * blockDim.x + threadIdx.x;
  if (e >= E) return;
  int d = dst[e];
  if ((unsigned)d < NN) atomicAdd(&deg[d], 1);
}

// -- parallel 3-phase exclusive scan of deg --
__global__ void scan_p1(const int* __restrict__ deg, int* __restrict__ bsum) {
  __shared__ int s[256];
  int t = threadIdx.x;
  int i = blockIdx.x * 256 + t;
  s[t] = (i < NN) ? deg[i] : 0;
  __syncthreads();
  #pragma unroll
  for (int off = 128; off > 0; off >>= 1) {
    if (t < off) s[t] += s[t + off];
    __syncthreads();
  }
  if (t == 0) bsum[blockIdx.x] = s[0];
}
__global__ void scan_p2(const int* __restrict__ bsum, int* __restrict__ boff,
                        int* __restrict__ total_out) {
  __shared__ int s[256];
  int t = threadIdx.x;
  s[t] = (t < SCAN_NB) ? bsum[t] : 0;
  __syncthreads();
  if (t == 0) {
    int r = 0;
    for (int i = 0; i < SCAN_NB; ++i) { int v = s[i]; s[i] = r; r += v; }
    total_out[0] = r;   // rowptr[NN]
  }
  __syncthreads();
  if (t < SCAN_NB) boff[t] = s[t];
}
__global__ void scan_p3(const int* __restrict__ deg, const int* __restrict__ boff,
                        int* __restrict__ rowptr, int* __restrict__ cursor) {
  __shared__ int s[256];
  int t = threadIdx.x;
  int i = blockIdx.x * 256 + t;
  int v = (i < NN) ? deg[i] : 0;
  s[t] = v;
  __syncthreads();
  #pragma unroll
  for (int off = 1; off < 256; off <<= 1) {
    int add = (t >= off) ? s[t - off] : 0;
    __syncthreads();
    s[t] += add;
    __syncthreads();
  }
  if (i < NN) {
    int pos = boff[blockIdx.x] + s[t] - v;   // exclusive
    rowptr[i] = pos;
    cursor[i] = pos;
  }
}

// csr entry = {edge id, src node}
__global__ void scatter_kernel(const int* __restrict__ src, const int* __restrict__ dst,
                               int* __restrict__ cursor, int2* __restrict__ csr2, int E) {
  int e = blockIdx.x * blockDim.x + threadIdx.x;
  if (e >= E) return;
  int d = dst[e];
  if ((unsigned)d >= NN) return;
  int s = src[e]; if ((unsigned)s >= NN) s = 0;
  int p = atomicAdd(&cursor[d], 1);
  if ((unsigned)p < (unsigned)E) csr2[p] = make_int2(e, s);
}

// ---- layer-1 fused logit+online-softmax+aggregate: wave per node, ONE pass ----
__global__ __launch_bounds__(256)
void agg1_all(const int2* __restrict__ csr2, const int* __restrict__ rowptr,
              const float4* __restrict__ es1, const float4* __restrict__ ed1,
              const bf16* __restrict__ Wh1, bf16* __restrict__ h1) {
  int wid = threadIdx.x >> 6, lane = threadIdx.x & 63;
  int node = blockIdx.x * 4 + wid;
  if (node >= NN) return;
  int b = rowptr[node], e = rowptr[node + 1];
  if (b < 0) b = 0; if (e > EE) e = EE;
  int h = lane >> 4;
  float4 ed4 = ed1[node];
  float ed = h == 0 ? ed4.x : h == 1 ? ed4.y : h == 2 ? ed4.z : ed4.w;
  float m = 0.f;  // e_max = max(seg_max, 0) -> init 0
  float sum = 0.f;
  float acc[8] = {};
  for (int j = b; j < e; ++j) {
    int2 c = csr2[j];
    float4 a4 = es1[c.y];
    float v = (h == 0 ? a4.x : h == 1 ? a4.y : h == 2 ? a4.z : a4.w) + ed;
    v = v >= 0.f ? v : 0.2f * v;
    float mnew = fmaxf(m, v);
    float corr = __expf(m - mnew);    // 1 when m unchanged
    float p = __expf(v - mnew);
    m = mnew;
    sum = sum * corr + p;
    bf16x8 r = *(const bf16x8*)(Wh1 + (size_t)c.y * C1 + lane * 8);
    #pragma unroll
    for (int k = 0; k < 8; ++k) acc[k] = acc[k] * corr + p * (float)r[k];
  }
  float scale = 1.f / (sum + 1e-8f);
  bf16x8 o;
  #pragma unroll
  for (int k = 0; k < 8; ++k) o[k] = (__bf16)(acc[k] * scale);
  *(bf16x8*)(h1 + (size_t)node * C1 + lane * 8) = o;
}

// ---- layer-2 fused logit+online-softmax+aggregate (H=1): wave per node ----
__global__ __launch_bounds__(256)
void agg2_all(const int2* __restrict__ csr2, const int* __restrict__ rowptr,
              const float* __restrict__ es2, const float* __restrict__ ed2,
              const bf16* __restrict__ Wh2, bf16* __restrict__ h2p,
              float* __restrict__ invs2, float* __restrict__ m2f) {
  int wid = threadIdx.x >> 6, lane = threadIdx.x & 63;
  int node = blockIdx.x * 4 + wid;
  if (node >= NN) return;
  int b = rowptr[node], e = rowptr[node + 1];
  if (b < 0) b = 0; if (e > EE) e = EE;
  float ed = ed2[node];
  float m = 0.f, sum = 0.f, a0 = 0.f, a1 = 0.f;
  for (int j = b; j < e; ++j) {
    int2 c = csr2[j];
    float v = es2[c.y] + ed;
    v = v >= 0.f ? v : 0.2f * v;
    float mnew = fmaxf(m, v);
    float corr = __expf(m - mnew);
    float p = __expf(v - mnew);
    m = mnew;
    sum = sum * corr + p;
    bf16x2v r = *(const bf16x2v*)(Wh2 + (size_t)c.y * HID + lane * 2);
    a0 = a0 * corr + p * (float)r[0];
    a1 = a1 * corr + p * (float)r[1];
  }
  float scale = 1.f / (sum + 1e-8f);
  bf16x2v o;
  o[0] = (__bf16)(a0 * scale);
  o[1] = (__bf16)(a1 * scale);
  *(bf16x2v*)(h2p + (size_t)node * HID + lane * 2) = o;
  if (lane == 0) { invs2[node] = scale; m2f[node] = m; }
}

// ---- attention output (edge-parallel, recompute logit+exp) ----
__global__ void attn_edge(const int* __restrict__ src, const int* __restrict__ dst,
                          const float* __restrict__ es2, const float* __restrict__ ed2,
                          const float* __restrict__ invs2, const float* __restrict__ m2f,
                          float* __restrict__ attn_out) {
  int e = blockIdx.x * 256 + threadIdx.x;
  if (e >= EE) return;
  int s = src[e]; if ((unsigned)s >= NN) s = 0;
  int d = dst[e]; if ((unsigned)d >= NN) d = 0;
  float v = es2[s] + ed2[d];
  v = v >= 0.f ? v : 0.2f * v;
  attn_out[e] = __expf(v - m2f[d]) * invs2[d];
}

// ---- ELU in place (bf16) + per-column fp32 sum/sumsq; blockDim == C ----
__global__ void elu_stats(bf16* __restrict__ X, float* __restrict__ cs, float* __restrict__ cq,
                          int Nrows, int C) {
  int c = threadIdx.x;
  int rpb = (Nrows + gridDim.x - 1) / gridDim.x;
  int r0 = blockIdx.x * rpb, r1 = min(r0 + rpb, Nrows);
  float s = 0.f, s2 = 0.f;
  for (int r = r0; r < r1; ++r) {
    size_t idx = (size_t)r * C + c;
    float v = b2f(X[idx]);
    v = v > 0.f ? v : expm1f(v);
    X[idx] = f2b(v);
    s += v; s2 += v * v;
  }
  atomicAdd(&cs[c], s);
  atomicAdd(&cq[c], s2);
}

__global__ void bn_apply(const bf16* __restrict__ in, bf16* __restrict__ out,
                         float* __restrict__ out2,
                         const float* __restrict__ cs, const float* __restrict__ cq,
                         const float* __restrict__ gamma, const float* __restrict__ beta,
                         int C, size_t total, float invN) {
  size_t i = (size_t)blockIdx.x * blockDim.x + threadIdx.x;
  if (i >= total) return;
  int c = (int)(i % C);
  float mu = cs[c] * invN;
  float var = cq[c] * invN - mu * mu;
  float v = (b2f(in[i]) - mu) * rsqrtf(fmaxf(var, 0.f) + 1e-5f) * gamma[c] + beta[c];
  out[i] = f2b(v);
  if (out2) out2[i] = v;
}

// ---- global mean pool: 32 rows/block, register-accumulate per graph run ----
__global__ __launch_bounds__(256)
void pool_kernel(const bf16* __restrict__ h2, const int* __restrict__ batch,
                 float* __restrict__ pooled) {
  int t = threadIdx.x;
  int f = t & 127, half = t >> 7;
  int r0 = blockIdx.x * 32;
  int g_cur = -1;
  float acc = 0.f;
  #pragma unroll
  for (int i = 0; i < 16; ++i) {
    int r = r0 + half + 2 * i;
    if (r >= NN) break;
    int g = batch[r]; if ((unsigned)g >= NGR) g = 0;
    float v = b2f(h2[(size_t)r * HID + f]);
    if (g != g_cur) {
      if (g_cur >= 0) atomicAdd(&pooled[g_cur * HID + f], acc);
      g_cur = g; acc = 0.f;
    }
    acc += v;
  }
  if (g_cur >= 0) atomicAdd(&pooled[g_cur * HID + f], acc);
}

// ---- per-graph counts via binary search on sorted batch ----
__global__ void cnt_kernel(const int* __restrict__ batch, float* __restrict__ cnt) {
  int g = threadIdx.x;
  if (g >= NGR) return;
  int a = 0, b = NN;
  while (a < b) { int m = (a + b) >> 1; if (batch[m] < g) a = m + 1; else b = m; }
  int lb = a;
  a = 0; b = NN;
  while (a < b) { int m = (a + b) >> 1; if (batch[m] <= g) a = m + 1; else b = m; }
  cnt[g] = (float)(a - lb);
}

// ---- classifier (tiny, single block) ----
__global__ void cls_kernel(const float* __restrict__ pooled, const float* __restrict__ cnt,
                           const float* __restrict__ w1, const float* __restrict__ b1,
                           const float* __restrict__ w2, const float* __restrict__ b2,
                           float* __restrict__ out) {
  __shared__ float repr[NGR * HID];
  __shared__ float hid[NGR * 64];
  int t = threadIdx.x;  // 128
  for (int i = t; i < NGR * HID; i += 128) {
    int g = i >> 7;
    repr[i] = pooled[i] / fmaxf(cnt[g], 1.f);
  }
  __syncthreads();
  for (int i = t; i < NGR * 64; i += 128) {
    int g = i >> 6, j = i & 63;
    float s = b1[j];
    for (int c = 0; c < HID; ++c) s += repr[g * HID + c] * w1[c * 64 + j];
    hid[i] = fmaxf(s, 0.f);
  }
  __syncthreads();
  if (t < NGR * 2) {
    int g = t >> 1, k = t & 1;
    float s = b2[k];
    for (int j = 0; j < 64; ++j) s += hid[g * 64 + j] * w2[j * 2 + k];
    out[t] = s;
  }
}

// ---- edge importance from fused PQ (N,256) ----
__global__ void eimp_kernel(const int* __restrict__ src, const int* __restrict__ dstp,
                            const bf16* __restrict__ PQ,
                            const float* __restrict__ b1, const float* __restrict__ w2,
                            const float* __restrict__ b2, float* __restrict__ out) {
  int wid = threadIdx.x >> 6, lane = threadIdx.x & 63;
  int e = blockIdx.x * 4 + wid;
  if (e >= EE) return;
  int s = src[e]; if ((unsigned)s >= NN) s = 0;
  int d = dstp[e]; if ((unsigned)d >= NN) d = 0;
  bf16x2v p2 = *(const bf16x2v*)(PQ + (size_t)s * 256 + lane * 2);
  bf16x2v q2 = *(const bf16x2v*)(PQ + (size_t)d * 256 + 128 + lane * 2);
  float acc = 0.f;
  #pragma unroll
  for (int r = 0; r < 2; ++r) {
    int j = lane * 2 + r;
    float hh = (float)p2[r] + (float)q2[r] + b1[j];
    hh = fmaxf(hh, 0.f);
    acc += hh * w2[j];
  }
  #pragma unroll
  for (int off = 32; off > 0; off >>= 1) acc += __shfl_xor(acc, off);
  if (lane == 0) {
    float z = acc + b2[0];
    out[e] = 1.f / (1.f + expf(-z));
  }
}

extern "C" void kernel_launch(void* const* d_in, const int* in_sizes, int n_in,
                              void* d_out, int out_size, void* d_ws, size_t ws_size,
                              hipStream_t stream) {
  const float* x      = (const float*)d_in[0];
  const int*   ei     = (const int*)d_in[1];
  const int*   batch  = (const int*)d_in[2];
  const float* W1     = (const float*)d_in[3];
  const float* a_src1 = (const float*)d_in[4];
  const float* a_dst1 = (const float*)d_in[5];
  const float* W2     = (const float*)d_in[6];
  const float* a_src2 = (const float*)d_in[7];
  const float* a_dst2 = (const float*)d_in[8];
  const float* bn1_g  = (const float*)d_in[9];
  const float* bn1_b  = (const float*)d_in[10];
  const float* bn2_g  = (const float*)d_in[11];
  const float* bn2_b  = (const float*)d_in[12];
  const float* cls_w1 = (const float*)d_in[13];
  const float* cls_b1 = (const float*)d_in[14];
  const float* cls_w2 = (const float*)d_in[15];
  const float* cls_b2 = (const float*)d_in[16];
  const float* ep_w1  = (const float*)d_in[17];
  const float* ep_b1  = (const float*)d_in[18];
  const float* ep_w2  = (const float*)d_in[19];
  const float* ep_b2  = (const float*)d_in[20];

  const int* srcp = ei;
  const int* dstp = ei + EE;

  // ---- workspace layout (bytes), peak ~118.9 MB, hazard-checked ----
  char* base = (char*)d_ws;
  bf16* xb  = (bf16*)(base);
  bf16* h1  = (bf16*)(base);
  bf16* Wh1 = (bf16*)(base + 51200000);
  bf16* Wh2 = (bf16*)(base + 51200000);   // (N,128) after agg1 (Wh1 dead)
  bf16* h2p = (bf16*)(base + 64000000);   // (N,128)
  bf16* h2  = (bf16*)(base + 76800000);   // (N,128)
  bf16* PQ  = (bf16*)(base + 51200000);   // (N,256) after bn2 (Wh2,h2p dead)
  float* m2f    = (float*)(base + 104000000);     // (N) layer-2 softmax max
  int* deg      = (int*)(base + 104400000);       // (N)  [adjacent to stats: one zero call]
  float* stats  = (float*)(base + 104600000);     // 3344 floats
  float* cs1 = stats,        *cq1 = stats + 512;
  float* cs2 = stats + 1024, *cq2 = stats + 1152;
  float* pooled = stats + 1280;                   // 16*128
  float* cnt    = stats + 3328;                   // 16
  float* es1    = (float*)(base + 104613376);     // (N,4)
  float* ed1    = (float*)(base + 105413376);     // (N,4)
  int* bsum     = (int*)(base + 106213376);       // scan scratch (dedicated)
  int* boff     = bsum + 256;
  float* es2    = (float*)(base + 112613376);     // (N)
  float* ed2    = (float*)(base + 112813376);     // (N)
  float* invs2  = (float*)(base + 114613376);     // (N)
  int* rowptr   = (int*)(base + 114813376);       // (N+1)
  int* cursor   = (int*)(base + 115013380);       // (N)
  int2* csr2    = (int2*)(base + 115213384);      // (E) {edge, src}
  bf16* B1t     = (bf16*)(base + 118413392);      // (512,288)
  bf16* B2t     = (bf16*)(base + 118708304);      // (128,512)
  bf16* BPt     = (bf16*)(base + 118839376);      // (256,128) -> ends 118,904,912

  float* out        = (float*)d_out;
  float* out_logits = out;                          // 32
  float* out_h2     = out + 32;                     // N*128
  float* out_imp    = out + 32 + (size_t)NN * HID;  // E
  float* out_attn   = out_imp + EE;                 // E

  // zero deg+stats in one call (adjacent; 53,344 words)
  zero_words<<<(53344 + 255) / 256, 256, 0, stream>>>((unsigned int*)deg, 53344);

  // prep: bf16 conversions / transposes
  conv_x<<<(NN * KP1 + 255) / 256, 256, 0, stream>>>(x, xb);
  prep_b1t<<<(C1 * KP1 + 255) / 256, 256, 0, stream>>>(W1, B1t);
  prep_b2t<<<(HID * C1 + 255) / 256, 256, 0, stream>>>(W2, B2t);
  prep_bpt<<<(256 * HID + 255) / 256, 256, 0, stream>>>(ep_w1, BPt);

  // CSR by destination (entries carry {edge, src}); parallel 3-phase scan
  count_kernel<<<(EE + 255) / 256, 256, 0, stream>>>(dstp, deg, EE);
  scan_p1<<<SCAN_NB, 256, 0, stream>>>(deg, bsum);
  scan_p2<<<1, 256, 0, stream>>>(bsum, boff, rowptr + NN);
  scan_p3<<<SCAN_NB, 256, 0, stream>>>(deg, boff, rowptr, cursor);
  scatter_kernel<<<(EE + 255) / 256, 256, 0, stream>>>(srcp, dstp, cursor, csr2, EE);

  // ---- layer 1: one GEMM (all heads) + fused logit/softmax/aggregate ----
  dim3 g1(C1 / 128, (NN + 127) / 128);
  gemm_mfma<<<g1, 256, 0, stream>>>(xb, B1t, Wh1, NN, KP1, C1);
  edot_all<<<(NN + 3) / 4, 256, 0, stream>>>(Wh1, a_src1, a_dst1, es1, ed1);
  agg1_all<<<(NN + 3) / 4, 256, 0, stream>>>(csr2, rowptr, (const float4*)es1,
                                             (const float4*)ed1, Wh1, h1);

  elu_stats<<<400, C1, 0, stream>>>(h1, cs1, cq1, NN, C1);
  {
    size_t total = (size_t)NN * C1;
    bn_apply<<<(unsigned)((total + 255) / 256), 256, 0, stream>>>(
        h1, h1, (float*)nullptr, cs1, cq1, bn1_g, bn1_b, C1, total, 1.f / NN);
  }

  // ---- layer 2 ----
  dim3 g2(1, (NN + 127) / 128);
  gemm_mfma<<<g2, 256, 0, stream>>>(h1, B2t, Wh2, NN, C1, HID);
  edot1<<<(NN + 3) / 4, 256, 0, stream>>>(Wh2, a_src2, a_dst2, es2, ed2);
  agg2_all<<<(NN + 3) / 4, 256, 0, stream>>>(csr2, rowptr, es2, ed2, Wh2, h2p, invs2, m2f);
  attn_edge<<<(EE + 255) / 256, 256, 0, stream>>>(srcp, dstp, es2, ed2, invs2, m2f, out_attn);

  elu_stats<<<400, HID, 0, stream>>>(h2p, cs2, cq2, NN, HID);
  {
    size_t total = (size_t)NN * HID;
    bn_apply<<<(unsigned)((total + 255) / 256), 256, 0, stream>>>(
        h2p, h2, out_h2, cs2, cq2, bn2_g, bn2_b, HID, total, 1.f / NN);
  }

  // ---- heads ----
  pool_kernel<<<(NN + 31) / 32, 256, 0, stream>>>(h2, batch, pooled);
  cnt_kernel<<<1, 64, 0, stream>>>(batch, cnt);
  cls_kernel<<<1, 128, 0, stream>>>(pooled, cnt, cls_w1, cls_b1, cls_w2, cls_b2, out_logits);

  dim3 gpq(2, (NN + 127) / 128);
  gemm_mfma<<<gpq, 256, 0, stream>>>(h2, BPt, PQ, NN, HID, 256);
  eimp_kernel<<<(EE + 3) / 4, 256, 0, stream>>>(srcp, dstp, PQ, ep_b1, ep_w2, ep_b2, out_imp);
}